// Round 5
// baseline (775.967 us; speedup 1.0000x reference)
//
#include <hip/hip_runtime.h>
#include <hip/hip_bf16.h>
#include <math.h>

#define T_  256
#define B_  32
#define V_  36
#define D_  128
#define H_  4
#define DK_ 32
#define S_  16
#define D4_ 512
#define K1_ 4608   // V_*D_
#define M_  8192   // B_*T_

typedef __hip_bfloat16 bf16;
typedef __attribute__((ext_vector_type(8))) short short8;
typedef __attribute__((ext_vector_type(4))) float f32x4;

__device__ __forceinline__ float gelu_f(float x){
    return 0.5f * x * (1.0f + erff(x * 0.70710678118654752f));
}

__device__ __forceinline__ float dot4(float4 a, float4 b){
    return fmaf(a.x, b.x, fmaf(a.y, b.y, fmaf(a.z, b.z, a.w * b.w)));
}

#define GLD16(g, l) __builtin_amdgcn_global_load_lds( \
    (const __attribute__((address_space(1))) void*)(g), \
    (__attribute__((address_space(3))) void*)(l), 16, 0, 0)

// ------------------- PE[(b,t),dd]  +  QQ[bt][80] = {q1=mk*xt | q0=mk} w/ fallback
__global__ void k_pe(const float* __restrict__ Xtimes, const float* __restrict__ Xtemp,
                     const int* __restrict__ mask, float* __restrict__ PE,
                     float* __restrict__ QQ){
    int bt = blockIdx.x;            // b*T_+t
    int b = bt >> 8, t = bt & 255;
    int tid = threadIdx.x;          // 0..127
    float x = Xtimes[t*B_ + b];
    int i = (tid < 64) ? tid : tid - 64;
    float sc = x * exp2f(-(float)i * (8.965784284662087f / 63.0f));
    PE[(size_t)bt*D_ + tid] = (tid < 64) ? sinf(sc) : cosf(sc);
    // wave 0 builds q1/q0
    if(tid < 64){
        float m = 0.f, xv = 0.f;
        if(tid < V_){
            m  = (float)mask[(t*B_ + b)*V_ + tid];
            xv = Xtemp[(t*B_ + b)*V_ + tid];
        }
        float s = m;
        #pragma unroll
        for(int off = 32; off > 0; off >>= 1) s += __shfl_xor(s, off);
        if(tid < V_){
            float q0 = (s > 0.f) ? m : 1.f;          // all-masked fallback
            float q1 = (s > 0.f) ? m*xv : xv;
            QQ[(size_t)bt*80 + tid]      = q1;
            QQ[(size_t)bt*80 + 40 + tid] = q0;
        }
    }
}

// ---------------- CB[b,v,dd] (orig) + cbP[b][u4][dd][4] (packed for k_v5)
__global__ void k_cb(const float* __restrict__ Xstatic, const float* __restrict__ embW,
                     const float* __restrict__ embB, const float* __restrict__ tempB,
                     float* __restrict__ CB, float* __restrict__ cbP){
    int bv = blockIdx.x;            // b*V_+v
    int b = bv / V_, v = bv - (bv / V_) * V_;
    int dd = threadIdx.x;
    int c = v*D_ + dd;
    float acc = tempB[c] + embB[c];
    #pragma unroll
    for(int s = 0; s < S_; ++s) acc = fmaf(Xstatic[b*S_+s], embW[s*K1_ + c], acc);
    CB[(size_t)bv*D_ + dd] = acc;
    cbP[(((size_t)b*9 + (v >> 2))*D_ + dd)*4 + (v & 3)] = acc;
}

// ---------------------------------------------- twP[u4][dd][4] packed temp_w
__global__ void k_packtw(const float* __restrict__ tempW, float* __restrict__ twP){
    int v = blockIdx.x, dd = threadIdx.x;
    twP[(((v >> 2))*D_ + dd)*4 + (v & 3)] = tempW[v*D_ + dd];
}

// ---------------- per (b,v): sm, sx, sp; H4 = (sx*temp_w + sm*CB + sp)/(sm+1)
__global__ void k_h4(const float* __restrict__ Xtemp, const int* __restrict__ mask,
                     const float* __restrict__ PE, const float* __restrict__ tempW,
                     const float* __restrict__ CB, float* __restrict__ H4){
    __shared__ float s_m[T_];
    __shared__ float s_r0[256];
    __shared__ float s_r1[256];
    __shared__ float s_p[2][D_];
    int bv = blockIdx.x;
    int b = bv / V_, v = bv - (bv / V_) * V_;
    int tid = threadIdx.x;          // = t
    float mval = (float)mask[(tid*B_ + b)*V_ + v];
    float xval = Xtemp[(tid*B_ + b)*V_ + v];
    s_m[tid]  = mval;
    s_r0[tid] = mval;
    s_r1[tid] = mval * xval;
    __syncthreads();
    for(int off = 128; off > 0; off >>= 1){
        if(tid < off){ s_r0[tid] += s_r0[tid+off]; s_r1[tid] += s_r1[tid+off]; }
        __syncthreads();
    }
    float sm = s_r0[0], sx = s_r1[0];
    int dd = tid & 127, half = tid >> 7;
    float sp = 0.f;
    for(int tt = half*128; tt < half*128 + 128; ++tt)
        sp = fmaf(s_m[tt], PE[(size_t)(b*T_ + tt)*D_ + dd], sp);
    s_p[half][dd] = sp;
    __syncthreads();
    if(tid < D_){
        float spv = s_p[0][tid] + s_p[1][tid];
        float h2 = fmaf(sx, tempW[v*D_ + tid], fmaf(sm, CB[(size_t)bv*D_ + tid], spv));
        H4[(size_t)bv*D_ + tid] = h2 / (sm + 1.0f);
    }
}

// ---------------------------------------------- q,k (scaled), mean_v per (b,v)
__global__ void k_qkv(const float* __restrict__ H4, const float* __restrict__ Wq,
                      const float* __restrict__ Wk, const float* __restrict__ Wv,
                      float* __restrict__ QS, float* __restrict__ KS, float* __restrict__ MV){
    __shared__ float s_h[D_];
    int bv = blockIdx.x;
    int o = threadIdx.x;
    s_h[o] = H4[(size_t)bv*D_ + o];
    __syncthreads();
    float aq = 0.f, ak = 0.f, av = 0.f;
    #pragma unroll 8
    for(int kk = 0; kk < D_; ++kk){
        float hv = s_h[kk];
        aq = fmaf(hv, Wq[kk*D_ + o], aq);
        ak = fmaf(hv, Wk[kk*D_ + o], ak);
        av = fmaf(hv, Wv[kk*D_ + o], av);
    }
    const float scale = 0.17677669529663687f;  // 1/sqrt(32)
    QS[(size_t)bv*D_ + o] = aq * scale;
    KS[(size_t)bv*D_ + o] = ak * scale;
    MV[(size_t)bv*D_ + o] = av;
}

// --------------- E[b,hv][u] (row stride 40): exp(A - rowmax(A over all u))
__global__ void k_attE(const float* __restrict__ QS, const float* __restrict__ KS,
                       float* __restrict__ E){
    int id = blockIdx.x;             // b*144 + hh*36 + v
    int v  = id % V_;
    int bh = id / V_;
    int hh = bh & 3, b = bh >> 2;
    int u = threadIdx.x;             // 0..63
    __shared__ float s_q[DK_];
    if(u < DK_) s_q[u] = QS[(size_t)(b*V_ + v)*D_ + hh*DK_ + u];
    __syncthreads();
    float a = -INFINITY;
    if(u < V_){
        a = 0.f;
        const float* kp = &KS[(size_t)(b*V_ + u)*D_ + hh*DK_];
        #pragma unroll
        for(int kk = 0; kk < DK_; ++kk) a = fmaf(s_q[kk], kp[kk], a);
    }
    float m = a;
    for(int off = 32; off > 0; off >>= 1) m = fmaxf(m, __shfl_xor(m, off));
    if(u < V_) E[(size_t)id*40 + u] = expf(a - m);
}

// ---------------- k_v5: block = (b, t-pair). LDS holds ONLY E (bank-safe).
// thread = (vq:4 waves, hh:4, j:16) -> dd0=hh*32+j, dd1=dd0+16, v = vq*9+vv
// out[bt, dd*36+v] = (sum_u E[hv,u]*(q1[t,u]*tw[u,dd]+q0[t,u]*cb[u,dd]))/den + MV + PE
__global__ __launch_bounds__(256) void k_v5(const float* __restrict__ QQ,
        const float* __restrict__ Eg, const float* __restrict__ twP,
        const float* __restrict__ cbP, const float* __restrict__ MV,
        const float* __restrict__ PE, bf16* __restrict__ V5){
    __shared__ float s_E[4*1300];     // [hh] base stride 1300 dw (20 mod 32)
    int blk = blockIdx.x;
    int b = blk >> 7, tp = blk & 127;
    int bt0 = b*T_ + tp*2;
    int tid = threadIdx.x;
    int vq = tid >> 6, hh = (tid >> 4) & 3, j = tid & 15;
    int dd0 = hh*32 + j, dd1 = dd0 + 16;

    for(int i = tid; i < 144*9; i += 256){
        int hv = i / 9, u4 = i - hv*9;
        int hq = hv / 36, vr = hv - hq*36;
        float4 e = *(const float4*)&Eg[((size_t)b*144 + hv)*40 + u4*4];
        *(float4*)&s_E[hq*1300 + (u4*36 + vr)*4] = e;
    }
    __syncthreads();

    float acc[2][2][9] = {};      // [t][ddp][vv]
    float den[2][9]    = {};      // [t][vv]
    #pragma unroll
    for(int u4 = 0; u4 < 9; ++u4){
        float4 q1a = *(const float4*)&QQ[(size_t)bt0*80 + u4*4];
        float4 q0a = *(const float4*)&QQ[(size_t)bt0*80 + 40 + u4*4];
        float4 q1b = *(const float4*)&QQ[(size_t)(bt0+1)*80 + u4*4];
        float4 q0b = *(const float4*)&QQ[(size_t)(bt0+1)*80 + 40 + u4*4];
        float4 tw0 = *(const float4*)&twP[(u4*D_ + dd0)*4];
        float4 tw1 = *(const float4*)&twP[(u4*D_ + dd1)*4];
        float4 cb0 = *(const float4*)&cbP[(((size_t)b*9 + u4)*D_ + dd0)*4];
        float4 cb1 = *(const float4*)&cbP[(((size_t)b*9 + u4)*D_ + dd1)*4];
        float4 w00, w01, w10, w11;   // [t][ddp]
        w00.x = fmaf(q1a.x, tw0.x, q0a.x*cb0.x); w00.y = fmaf(q1a.y, tw0.y, q0a.y*cb0.y);
        w00.z = fmaf(q1a.z, tw0.z, q0a.z*cb0.z); w00.w = fmaf(q1a.w, tw0.w, q0a.w*cb0.w);
        w01.x = fmaf(q1a.x, tw1.x, q0a.x*cb1.x); w01.y = fmaf(q1a.y, tw1.y, q0a.y*cb1.y);
        w01.z = fmaf(q1a.z, tw1.z, q0a.z*cb1.z); w01.w = fmaf(q1a.w, tw1.w, q0a.w*cb1.w);
        w10.x = fmaf(q1b.x, tw0.x, q0b.x*cb0.x); w10.y = fmaf(q1b.y, tw0.y, q0b.y*cb0.y);
        w10.z = fmaf(q1b.z, tw0.z, q0b.z*cb0.z); w10.w = fmaf(q1b.w, tw0.w, q0b.w*cb0.w);
        w11.x = fmaf(q1b.x, tw1.x, q0b.x*cb1.x); w11.y = fmaf(q1b.y, tw1.y, q0b.y*cb1.y);
        w11.z = fmaf(q1b.z, tw1.z, q0b.z*cb1.z); w11.w = fmaf(q1b.w, tw1.w, q0b.w*cb1.w);
        int ebase = hh*1300 + (u4*36 + vq*9)*4;
        #pragma unroll
        for(int vv = 0; vv < 9; ++vv){
            float4 e = *(const float4*)&s_E[ebase + vv*4];
            den[0][vv] += dot4(e, q0a);
            den[1][vv] += dot4(e, q0b);
            acc[0][0][vv] += dot4(e, w00);
            acc[0][1][vv] += dot4(e, w01);
            acc[1][0][vv] += dot4(e, w10);
            acc[1][1][vv] += dot4(e, w11);
        }
    }
    // epilogue
    float mv[2][9];
    #pragma unroll
    for(int vv = 0; vv < 9; ++vv){
        mv[0][vv] = MV[((size_t)b*V_ + vq*9 + vv)*D_ + dd0];
        mv[1][vv] = MV[((size_t)b*V_ + vq*9 + vv)*D_ + dd1];
    }
    #pragma unroll
    for(int t = 0; t < 2; ++t){
        size_t bt = bt0 + t;
        float rd[9];
        #pragma unroll
        for(int vv = 0; vv < 9; ++vv) rd[vv] = 1.0f / den[t][vv];
        float pe0 = PE[bt*D_ + dd0];
        float pe1 = PE[bt*D_ + dd1];
        bf16* op0 = V5 + bt*K1_ + dd0*V_ + vq*9;
        bf16* op1 = V5 + bt*K1_ + dd1*V_ + vq*9;
        #pragma unroll
        for(int vv = 0; vv < 9; ++vv){
            op0[vv] = __float2bfloat16(fmaf(acc[t][0][vv], rd[vv], mv[0][vv] + pe0));
            op1[vv] = __float2bfloat16(fmaf(acc[t][1][vv], rd[vv], mv[1][vv] + pe1));
        }
    }
}

// ------------------------------------------- W1 (f32, N x K) -> bf16 (N x K)
__global__ void k_cast(const float* __restrict__ src, bf16* __restrict__ dst){
    int i = (blockIdx.x*256 + threadIdx.x)*4;   // n = 512*4608, exact
    float4 v = *(const float4*)&src[i];
    dst[i+0] = __float2bfloat16(v.x);
    dst[i+1] = __float2bfloat16(v.y);
    dst[i+2] = __float2bfloat16(v.z);
    dst[i+3] = __float2bfloat16(v.w);
}

// ---------------- y1 = V5 @ W1^T + b1 ; MFMA 128x64 tile, BK=64, XOR-swizzled LDS
__global__ __launch_bounds__(256) void k_gemm1(const bf16* __restrict__ A,
        const bf16* __restrict__ Bw, const float* __restrict__ bias,
        float* __restrict__ C){
    __shared__ __align__(16) bf16 As[128*64];    // 16 KB
    __shared__ __align__(16) bf16 Bs[64*64];     // 8 KB
    int bid = blockIdx.x;
    int L = (bid & 7)*64 + (bid >> 3);           // XCD-chunk swizzle (512%8==0)
    int nb = L & 7, mb = L >> 3;
    int m0 = mb * 128, n0 = nb * 64;
    int tid = threadIdx.x;
    int w = tid >> 6, l = tid & 63;
    int wr = w >> 1, wc = w & 1;                 // wave -> 64x32 sub-tile
    int r = l & 15, kg = l >> 4;
    f32x4 acc[4][2] = {};

    // staging: slot s (16B): row = s>>3, col8 = s&7; source pre-swizzled
    int sA0 = 0*256 + w*64 + l;
    int sA1 = 1*256 + w*64 + l;
    int sA2 = 2*256 + w*64 + l;
    int sA3 = 3*256 + w*64 + l;
    int sB0 = 0*256 + w*64 + l;
    int sB1 = 1*256 + w*64 + l;
    const bf16* gA0 = A + (size_t)(m0 + (sA0>>3))*K1_ + ((sA0&7) ^ ((sA0>>3)&7))*8;
    const bf16* gA1 = A + (size_t)(m0 + (sA1>>3))*K1_ + ((sA1&7) ^ ((sA1>>3)&7))*8;
    const bf16* gA2 = A + (size_t)(m0 + (sA2>>3))*K1_ + ((sA2&7) ^ ((sA2>>3)&7))*8;
    const bf16* gA3 = A + (size_t)(m0 + (sA3>>3))*K1_ + ((sA3&7) ^ ((sA3>>3)&7))*8;
    const bf16* gB0 = Bw + (size_t)(n0 + (sB0>>3))*K1_ + ((sB0&7) ^ ((sB0>>3)&7))*8;
    const bf16* gB1 = Bw + (size_t)(n0 + (sB1>>3))*K1_ + ((sB1&7) ^ ((sB1>>3)&7))*8;
    bf16* lA0 = &As[(0*256 + w*64)*8];
    bf16* lA1 = &As[(1*256 + w*64)*8];
    bf16* lA2 = &As[(2*256 + w*64)*8];
    bf16* lA3 = &As[(3*256 + w*64)*8];
    bf16* lB0 = &Bs[(0*256 + w*64)*8];
    bf16* lB1 = &Bs[(1*256 + w*64)*8];

    for(int k0 = 0; k0 < K1_; k0 += 64){
        GLD16(gA0 + k0, lA0);
        GLD16(gA1 + k0, lA1);
        GLD16(gA2 + k0, lA2);
        GLD16(gA3 + k0, lA3);
        GLD16(gB0 + k0, lB0);
        GLD16(gB1 + k0, lB1);
        __syncthreads();
        short8 af[2][4], bfr[2][2];
        #pragma unroll
        for(int kh = 0; kh < 2; ++kh){
            #pragma unroll
            for(int m = 0; m < 4; ++m){
                int row = wr*64 + m*16 + r;
                int e = (row*64 + kh*32 + kg*8) ^ ((r & 7) << 3);
                af[kh][m] = *(const short8*)&As[e];
            }
            #pragma unroll
            for(int n = 0; n < 2; ++n){
                int row = wc*32 + n*16 + r;
                int e = (row*64 + kh*32 + kg*8) ^ ((r & 7) << 3);
                bfr[kh][n] = *(const short8*)&Bs[e];
            }
        }
        #pragma unroll
        for(int kh = 0; kh < 2; ++kh)
            #pragma unroll
            for(int m = 0; m < 4; ++m)
                #pragma unroll
                for(int n = 0; n < 2; ++n)
                    acc[m][n] = __builtin_amdgcn_mfma_f32_16x16x32_bf16(
                                    af[kh][m], bfr[kh][n], acc[m][n], 0, 0, 0);
        __syncthreads();
    }
    // C/D layout: col = lane&15, row = (lane>>4)*4 + i   [m89]
    #pragma unroll
    for(int m = 0; m < 4; ++m){
        int rowb = m0 + wr*64 + m*16 + kg*4;
        #pragma unroll
        for(int n = 0; n < 2; ++n){
            int col = n0 + wc*32 + n*16 + r;
            float bv = bias[col];
            #pragma unroll
            for(int i = 0; i < 4; ++i)
                C[(size_t)(rowb + i)*D4_ + col] = acc[m][n][i] + bv;
        }
    }
}

// -------------------------------------- per-channel sum / sumsq over M rows
__global__ void k_stats(const float* __restrict__ X, int C, float* __restrict__ ST){
    int r0 = blockIdx.x * 32;
    int tid = threadIdx.x;
    for(int c = tid; c < C; c += 256){
        float s = 0.f, q = 0.f;
        for(int r = 0; r < 32; ++r){
            float v = X[(size_t)(r0 + r)*C + c];
            s += v;
            q = fmaf(v, v, q);
        }
        atomicAdd(&ST[c], s);
        atomicAdd(&ST[C + c], q);
    }
}

__global__ void k_bnfin(const float* __restrict__ ST, const float* __restrict__ g,
                        const float* __restrict__ bb, int C, float* __restrict__ P){
    int c = blockIdx.x * blockDim.x + threadIdx.x;
    if(c < C){
        float mu  = ST[c] * (1.0f / M_);
        float var = ST[C + c] * (1.0f / M_) - mu*mu;
        float sc  = g[c] * rsqrtf(var + 1e-5f);
        P[c]     = sc;
        P[C + c] = bb[c] - mu*sc;
    }
}

// ---------------- y2 = gelu(BN1(y1)) @ W2^T + b2 ; 64x64 tile, BN+gelu on load
__global__ __launch_bounds__(256) void k_gemm2(const float* __restrict__ Y1,
        const float* __restrict__ P1, const float* __restrict__ W2,
        const float* __restrict__ b2, float* __restrict__ Z){
    __shared__ __align__(16) float As[16][68];
    __shared__ __align__(16) float Bs[16][68];
    int tid = threadIdx.x;
    int m0 = blockIdx.x * 64, n0 = blockIdx.y * 64;
    float acc[4][4] = {};
    int arow = tid >> 2, ac = (tid & 3) * 4;
    int ty = tid >> 4, tx = tid & 15;
    for(int k0 = 0; k0 < D4_; k0 += 16){
        float4 a = *(const float4*)&Y1[(size_t)(m0 + arow)*D4_ + k0 + ac];
        float4 w = *(const float4*)&W2[(size_t)(n0 + arow)*D4_ + k0 + ac];
        As[ac+0][arow] = gelu_f(fmaf(a.x, P1[k0+ac+0], P1[D4_ + k0+ac+0]));
        As[ac+1][arow] = gelu_f(fmaf(a.y, P1[k0+ac+1], P1[D4_ + k0+ac+1]));
        As[ac+2][arow] = gelu_f(fmaf(a.z, P1[k0+ac+2], P1[D4_ + k0+ac+2]));
        As[ac+3][arow] = gelu_f(fmaf(a.w, P1[k0+ac+3], P1[D4_ + k0+ac+3]));
        Bs[ac+0][arow] = w.x; Bs[ac+1][arow] = w.y;
        Bs[ac+2][arow] = w.z; Bs[ac+3][arow] = w.w;
        __syncthreads();
        #pragma unroll
        for(int kk = 0; kk < 16; ++kk){
            float4 x = *(const float4*)&As[kk][ty*4];
            float4 y = *(const float4*)&Bs[kk][tx*4];
            float av[4] = {x.x,x.y,x.z,x.w};
            float bv[4] = {y.x,y.y,y.z,y.w};
            #pragma unroll
            for(int i = 0; i < 4; ++i)
                #pragma unroll
                for(int j = 0; j < 4; ++j)
                    acc[i][j] = fmaf(av[i], bv[j], acc[i][j]);
        }
        __syncthreads();
    }
    #pragma unroll
    for(int i = 0; i < 4; ++i){
        int row = m0 + ty*4 + i, col = n0 + tx*4;
        float4 o;
        o.x = acc[i][0] + b2[col+0];
        o.y = acc[i][1] + b2[col+1];
        o.z = acc[i][2] + b2[col+2];
        o.w = acc[i][3] + b2[col+3];
        *(float4*)&Z[(size_t)row*D_ + col] = o;
    }
}

// ------- z = gelu(BN2(y2)); LN over d; out[b,o,t] = z + zn (t-contig float4)
__global__ __launch_bounds__(256) void k_final(const float* __restrict__ Z,
        const float* __restrict__ P2, const float* __restrict__ lng,
        const float* __restrict__ lnb, float* __restrict__ out){
    __shared__ float s_z[64*129];
    __shared__ float s_mu[64];
    __shared__ float s_rs[64];
    int b  = blockIdx.x >> 2;
    int t0 = (blockIdx.x & 3) * 64;
    int tid = threadIdx.x;
    #pragma unroll
    for(int i = 0; i < 32; ++i){
        int idx = tid + i*256;
        int row = idx >> 7, col = idx & 127;
        float v = Z[(size_t)(b*T_ + t0 + row)*D_ + col];
        s_z[row*129 + col] = gelu_f(fmaf(v, P2[col], P2[D_ + col]));
    }
    __syncthreads();
    if(tid < 64){
        float s = 0.f;
        #pragma unroll
        for(int j = 0; j < D_; ++j) s += s_z[tid*129 + j];
        float mu = s * (1.0f / D_);
        float q = 0.f;
        #pragma unroll
        for(int j = 0; j < D_; ++j){
            float dv = s_z[tid*129 + j] - mu;
            q = fmaf(dv, dv, q);
        }
        s_mu[tid] = mu;
        s_rs[tid] = rsqrtf(q * (1.0f / D_) + 1e-5f);
    }
    __syncthreads();
    int o  = tid & 127;
    int th = tid >> 7;               // 0/1 -> t-half of the 64-row tile
    float g  = lng[o];
    float be = lnb[o];
    #pragma unroll
    for(int j4 = 0; j4 < 8; ++j4){
        float4 ov;
        #pragma unroll
        for(int q = 0; q < 4; ++q){
            int tt = th*32 + j4*4 + q;
            float z = s_z[tt*129 + o];
            float zn = fmaf((z - s_mu[tt]) * s_rs[tt], g, be);
            (&ov.x)[q] = z + zn;
        }
        *(float4*)&out[((size_t)(b*D_ + o))*T_ + t0 + th*32 + j4*4] = ov;
    }
}

extern "C" void kernel_launch(void* const* d_in, const int* in_sizes, int n_in,
                              void* d_out, int out_size, void* d_ws, size_t ws_size,
                              hipStream_t stream){
    const float* Xtemp   = (const float*)d_in[0];
    const float* Xtimes  = (const float*)d_in[1];
    const float* Xstatic = (const float*)d_in[2];
    const int*   mask    = (const int*)  d_in[3];
    const float* Wq      = (const float*)d_in[4];
    const float* Wk      = (const float*)d_in[5];
    const float* Wv      = (const float*)d_in[6];
    const float* tempW   = (const float*)d_in[7];
    const float* tempB   = (const float*)d_in[8];
    const float* embW    = (const float*)d_in[9];
    const float* embB    = (const float*)d_in[10];
    const float* W1      = (const float*)d_in[11];
    const float* b1      = (const float*)d_in[12];
    const float* bn1g    = (const float*)d_in[13];
    const float* bn1b    = (const float*)d_in[14];
    const float* W2      = (const float*)d_in[15];
    const float* b2      = (const float*)d_in[16];
    const float* bn2g    = (const float*)d_in[17];
    const float* bn2b    = (const float*)d_in[18];
    const float* lng     = (const float*)d_in[19];
    const float* lnb     = (const float*)d_in[20];
    float* out = (float*)d_out;

    float* w = (float*)d_ws;
    float* PE = w;  w += (size_t)M_ * D_;            // 1,048,576 f32
    float* CB = w;  w += (size_t)B_ * V_ * D_;       // 147,456
    float* cbP= w;  w += (size_t)B_ * 9 * D_ * 4;    // 147,456
    float* twP= w;  w += (size_t)9 * D_ * 4;         // 4,608
    float* H4 = w;  w += (size_t)B_ * V_ * D_;
    float* QS = w;  w += (size_t)B_ * V_ * D_;
    float* KS = w;  w += (size_t)B_ * V_ * D_;
    float* MV = w;  w += (size_t)B_ * V_ * D_;
    float* E  = w;  w += (size_t)B_ * 144 * 40;      // 184,320 (padded rows)
    float* QQ = w;  w += (size_t)M_ * 80;            // 655,360
    float* Y1 = w;  w += (size_t)M_ * D4_;           // 4,194,304
    float* Z1 = w;  w += (size_t)M_ * D_;            // 1,048,576
    float* ST1 = w; w += 1024;
    float* ST2 = w; w += 256;
    float* P1  = w; w += 1024;
    float* P2  = w; w += 256;
    bf16* V5  = (bf16*)w;                            // 75.5 MB
    bf16* W1b = (bf16*)(w + ((size_t)M_ * K1_) / 2); // 4.7 MB

    hipMemsetAsync(ST1, 0, (1024 + 256) * sizeof(float), stream);

    k_pe    <<<M_, D_, 0, stream>>>(Xtimes, Xtemp, mask, PE, QQ);
    k_cb    <<<B_*V_, D_, 0, stream>>>(Xstatic, embW, embB, tempB, CB, cbP);
    k_packtw<<<V_, D_, 0, stream>>>(tempW, twP);
    k_cast  <<<(D4_*K1_)/1024, 256, 0, stream>>>(W1, W1b);
    k_h4    <<<B_*V_, 256, 0, stream>>>(Xtemp, mask, PE, tempW, CB, H4);
    k_qkv   <<<B_*V_, D_, 0, stream>>>(H4, Wq, Wk, Wv, QS, KS, MV);
    k_attE  <<<B_*H_*V_, 64, 0, stream>>>(QS, KS, E);
    k_v5    <<<B_*(T_/2), 256, 0, stream>>>(QQ, E, twP, cbP, MV, PE, V5);
    k_gemm1 <<<512, 256, 0, stream>>>(V5, W1b, b1, Y1);
    k_stats <<<M_/32, 256, 0, stream>>>(Y1, D4_, ST1);
    k_bnfin <<<2, 256, 0, stream>>>(ST1, bn1g, bn1b, D4_, P1);
    k_gemm2 <<<dim3(M_/64, D_/64), 256, 0, stream>>>(Y1, P1, W2, b2, Z1);
    k_stats <<<M_/32, 256, 0, stream>>>(Z1, D_, ST2);
    k_bnfin <<<1, 128, 0, stream>>>(ST2, bn2g, bn2b, D_, P2);
    k_final <<<B_*(T_/64), 256, 0, stream>>>(Z1, P2, lng, lnb, out);
}

// Round 11
// 390.321 us; speedup vs baseline: 1.9880x; 1.9880x over previous
//
#include <hip/hip_runtime.h>
#include <hip/hip_bf16.h>
#include <math.h>

#define T_  256
#define B_  32
#define V_  36
#define D_  128
#define H_  4
#define DK_ 32
#define S_  16
#define D4_ 512
#define K1_ 4608   // V_*D_
#define M_  8192   // B_*T_

typedef __hip_bfloat16 bf16;
typedef __attribute__((ext_vector_type(8))) short short8;
typedef __attribute__((ext_vector_type(4))) float f32x4;

__device__ __forceinline__ float gelu_f(float x){
    return 0.5f * x * (1.0f + erff(x * 0.70710678118654752f));
}

__device__ __forceinline__ float dot4(float4 a, float4 b){
    return fmaf(a.x, b.x, fmaf(a.y, b.y, fmaf(a.z, b.z, a.w * b.w)));
}

__device__ __forceinline__ unsigned short bf16_bits(float x){
    bf16 h = __float2bfloat16(x);
    return *reinterpret_cast<unsigned short*>(&h);
}

#define GLD16(g, l) __builtin_amdgcn_global_load_lds( \
    (const __attribute__((address_space(1))) void*)(g), \
    (__attribute__((address_space(3))) void*)(l), 16, 0, 0)

// ------------------- PE[(b,t),dd]  +  QQ[bt][80] = {q1=mk*xt | q0=mk} w/ fallback
__global__ void k_pe(const float* __restrict__ Xtimes, const float* __restrict__ Xtemp,
                     const int* __restrict__ mask, float* __restrict__ PE,
                     float* __restrict__ QQ){
    int bt = blockIdx.x;            // b*T_+t
    int b = bt >> 8, t = bt & 255;
    int tid = threadIdx.x;          // 0..127
    float x = Xtimes[t*B_ + b];
    int i = (tid < 64) ? tid : tid - 64;
    float sc = x * exp2f(-(float)i * (8.965784284662087f / 63.0f));
    PE[(size_t)bt*D_ + tid] = (tid < 64) ? sinf(sc) : cosf(sc);
    // wave 0 builds q1/q0
    if(tid < 64){
        float m = 0.f, xv = 0.f;
        if(tid < V_){
            m  = (float)mask[(t*B_ + b)*V_ + tid];
            xv = Xtemp[(t*B_ + b)*V_ + tid];
        }
        float s = m;
        #pragma unroll
        for(int off = 32; off > 0; off >>= 1) s += __shfl_xor(s, off);
        if(tid < V_){
            float q0 = (s > 0.f) ? m : 1.f;          // all-masked fallback
            float q1 = (s > 0.f) ? m*xv : xv;
            QQ[(size_t)bt*80 + tid]      = q1;
            QQ[(size_t)bt*80 + 40 + tid] = q0;
        }
    }
}

// ---------------- CB[b,v,dd] (orig) + cbP[b][u4][dd][4] (packed for k_v5)
__global__ void k_cb(const float* __restrict__ Xstatic, const float* __restrict__ embW,
                     const float* __restrict__ embB, const float* __restrict__ tempB,
                     float* __restrict__ CB, float* __restrict__ cbP){
    int bv = blockIdx.x;            // b*V_+v
    int b = bv / V_, v = bv - (bv / V_) * V_;
    int dd = threadIdx.x;
    int c = v*D_ + dd;
    float acc = tempB[c] + embB[c];
    #pragma unroll
    for(int s = 0; s < S_; ++s) acc = fmaf(Xstatic[b*S_+s], embW[s*K1_ + c], acc);
    CB[(size_t)bv*D_ + dd] = acc;
    cbP[(((size_t)b*9 + (v >> 2))*D_ + dd)*4 + (v & 3)] = acc;
}

// ---------------------------------------------- twP[u4][dd][4] packed temp_w
__global__ void k_packtw(const float* __restrict__ tempW, float* __restrict__ twP){
    int v = blockIdx.x, dd = threadIdx.x;
    twP[(((v >> 2))*D_ + dd)*4 + (v & 3)] = tempW[v*D_ + dd];
}

// ---------------- per (b,v): sm, sx, sp; H4 = (sx*temp_w + sm*CB + sp)/(sm+1)
__global__ void k_h4(const float* __restrict__ Xtemp, const int* __restrict__ mask,
                     const float* __restrict__ PE, const float* __restrict__ tempW,
                     const float* __restrict__ CB, float* __restrict__ H4){
    __shared__ float s_m[T_];
    __shared__ float s_r0[256];
    __shared__ float s_r1[256];
    __shared__ float s_p[2][D_];
    int bv = blockIdx.x;
    int b = bv / V_, v = bv - (bv / V_) * V_;
    int tid = threadIdx.x;          // = t
    float mval = (float)mask[(tid*B_ + b)*V_ + v];
    float xval = Xtemp[(tid*B_ + b)*V_ + v];
    s_m[tid]  = mval;
    s_r0[tid] = mval;
    s_r1[tid] = mval * xval;
    __syncthreads();
    for(int off = 128; off > 0; off >>= 1){
        if(tid < off){ s_r0[tid] += s_r0[tid+off]; s_r1[tid] += s_r1[tid+off]; }
        __syncthreads();
    }
    float sm = s_r0[0], sx = s_r1[0];
    int dd = tid & 127, half = tid >> 7;
    float sp = 0.f;
    for(int tt = half*128; tt < half*128 + 128; ++tt)
        sp = fmaf(s_m[tt], PE[(size_t)(b*T_ + tt)*D_ + dd], sp);
    s_p[half][dd] = sp;
    __syncthreads();
    if(tid < D_){
        float spv = s_p[0][tid] + s_p[1][tid];
        float h2 = fmaf(sx, tempW[v*D_ + tid], fmaf(sm, CB[(size_t)bv*D_ + tid], spv));
        H4[(size_t)bv*D_ + tid] = h2 / (sm + 1.0f);
    }
}

// ---------------------------------------------- q,k (scaled), mean_v per (b,v)
__global__ void k_qkv(const float* __restrict__ H4, const float* __restrict__ Wq,
                      const float* __restrict__ Wk, const float* __restrict__ Wv,
                      float* __restrict__ QS, float* __restrict__ KS, float* __restrict__ MV){
    __shared__ float s_h[D_];
    int bv = blockIdx.x;
    int o = threadIdx.x;
    s_h[o] = H4[(size_t)bv*D_ + o];
    __syncthreads();
    float aq = 0.f, ak = 0.f, av = 0.f;
    #pragma unroll 8
    for(int kk = 0; kk < D_; ++kk){
        float hv = s_h[kk];
        aq = fmaf(hv, Wq[kk*D_ + o], aq);
        ak = fmaf(hv, Wk[kk*D_ + o], ak);
        av = fmaf(hv, Wv[kk*D_ + o], av);
    }
    const float scale = 0.17677669529663687f;  // 1/sqrt(32)
    QS[(size_t)bv*D_ + o] = aq * scale;
    KS[(size_t)bv*D_ + o] = ak * scale;
    MV[(size_t)bv*D_ + o] = av;
}

// --------------- E[b,hv][u] (row stride 40): exp(A - rowmax(A over all u))
__global__ void k_attE(const float* __restrict__ QS, const float* __restrict__ KS,
                       float* __restrict__ E){
    int id = blockIdx.x;             // b*144 + hh*36 + v
    int v  = id % V_;
    int bh = id / V_;
    int hh = bh & 3, b = bh >> 2;
    int u = threadIdx.x;             // 0..63
    __shared__ float s_q[DK_];
    if(u < DK_) s_q[u] = QS[(size_t)(b*V_ + v)*D_ + hh*DK_ + u];
    __syncthreads();
    float a = -INFINITY;
    if(u < V_){
        a = 0.f;
        const float* kp = &KS[(size_t)(b*V_ + u)*D_ + hh*DK_];
        #pragma unroll
        for(int kk = 0; kk < DK_; ++kk) a = fmaf(s_q[kk], kp[kk], a);
    }
    float m = a;
    for(int off = 32; off > 0; off >>= 1) m = fmaxf(m, __shfl_xor(m, off));
    if(u < V_) E[(size_t)id*40 + u] = expf(a - m);
}

// ---------------- k_v5 v3: block = one (b,t). LDS holds ONLY E. Low-VGPR.
// thread = (vq:4, hh:4, j:16) -> dd0=hh*32+j, dd1=dd0+16, v = vq*9+vv
// out[bt, dd*36+v] = (sum_u E[hv,u]*(q1[u]*tw[u,dd]+q0[u]*cb[u,dd]))/den + MV + PE
__global__ __launch_bounds__(256) void k_v5(const float* __restrict__ QQ,
        const float* __restrict__ Eg, const float* __restrict__ twP,
        const float* __restrict__ cbP, const float* __restrict__ MV,
        const float* __restrict__ PE, bf16* __restrict__ V5){
    __shared__ float s_E[4*1300];     // [hh] base stride 1300 dw (20 mod 32)
    int bt = blockIdx.x;
    int b = bt >> 8;
    int tid = threadIdx.x;
    int vq = tid >> 6, hh = (tid >> 4) & 3, j = tid & 15;
    int dd0 = hh*32 + j, dd1 = dd0 + 16;

    for(int i = tid; i < 144*9; i += 256){
        int hv = i / 9, u4 = i - hv*9;
        int hq = hv / 36, vr = hv - hq*36;
        float4 e = *(const float4*)&Eg[((size_t)b*144 + hv)*40 + u4*4];
        *(float4*)&s_E[hq*1300 + (u4*36 + vr)*4] = e;
    }
    __syncthreads();

    float acc0[9] = {}, acc1[9] = {}, den[9] = {};
    const float* qq = &QQ[(size_t)bt*80];
    #pragma unroll 1                  // keep register pressure flat
    for(int u4 = 0; u4 < 9; ++u4){
        float4 q1 = *(const float4*)&qq[u4*4];
        float4 q0 = *(const float4*)&qq[40 + u4*4];
        float4 tw0 = *(const float4*)&twP[(u4*D_ + dd0)*4];
        float4 tw1 = *(const float4*)&twP[(u4*D_ + dd1)*4];
        float4 cb0 = *(const float4*)&cbP[(((size_t)b*9 + u4)*D_ + dd0)*4];
        float4 cb1 = *(const float4*)&cbP[(((size_t)b*9 + u4)*D_ + dd1)*4];
        float4 w0, w1;
        w0.x = fmaf(q1.x, tw0.x, q0.x*cb0.x); w0.y = fmaf(q1.y, tw0.y, q0.y*cb0.y);
        w0.z = fmaf(q1.z, tw0.z, q0.z*cb0.z); w0.w = fmaf(q1.w, tw0.w, q0.w*cb0.w);
        w1.x = fmaf(q1.x, tw1.x, q0.x*cb1.x); w1.y = fmaf(q1.y, tw1.y, q0.y*cb1.y);
        w1.z = fmaf(q1.z, tw1.z, q0.z*cb1.z); w1.w = fmaf(q1.w, tw1.w, q0.w*cb1.w);
        const float* eb = &s_E[hh*1300 + (u4*36 + vq*9)*4];
        #pragma unroll
        for(int vv = 0; vv < 9; ++vv){
            float4 e = *(const float4*)&eb[vv*4];
            den[vv]  += dot4(e, q0);
            acc0[vv] += dot4(e, w0);
            acc1[vv] += dot4(e, w1);
        }
    }
    float pe0 = PE[(size_t)bt*D_ + dd0];
    float pe1 = PE[(size_t)bt*D_ + dd1];
    bf16* op0 = V5 + (size_t)bt*K1_ + dd0*V_ + vq*9;
    bf16* op1 = V5 + (size_t)bt*K1_ + dd1*V_ + vq*9;
    #pragma unroll
    for(int vv = 0; vv < 9; ++vv){
        float rd = 1.0f / den[vv];
        float m0v = MV[((size_t)b*V_ + vq*9 + vv)*D_ + dd0];
        float m1v = MV[((size_t)b*V_ + vq*9 + vv)*D_ + dd1];
        op0[vv] = __float2bfloat16(fmaf(acc0[vv], rd, m0v + pe0));
        op1[vv] = __float2bfloat16(fmaf(acc1[vv], rd, m1v + pe1));
    }
}

// ------------------------------------------- f32 -> bf16 (4 elems/thread)
__global__ void k_cast(const float* __restrict__ src, bf16* __restrict__ dst){
    int i = (blockIdx.x*256 + threadIdx.x)*4;
    float4 v = *(const float4*)&src[i];
    dst[i+0] = __float2bfloat16(v.x);
    dst[i+1] = __float2bfloat16(v.y);
    dst[i+2] = __float2bfloat16(v.z);
    dst[i+3] = __float2bfloat16(v.w);
}

// ---------------- y1 = V5 @ W1^T + b1 ; MFMA 128x64 tile, BK=64, XOR-swizzled LDS
__global__ __launch_bounds__(256) void k_gemm1(const bf16* __restrict__ A,
        const bf16* __restrict__ Bw, const float* __restrict__ bias,
        float* __restrict__ C){
    __shared__ __align__(16) bf16 As[128*64];    // 16 KB
    __shared__ __align__(16) bf16 Bs[64*64];     // 8 KB
    int bid = blockIdx.x;
    int L = (bid & 7)*64 + (bid >> 3);           // XCD-chunk swizzle (512%8==0)
    int nb = L & 7, mb = L >> 3;
    int m0 = mb * 128, n0 = nb * 64;
    int tid = threadIdx.x;
    int w = tid >> 6, l = tid & 63;
    int wr = w >> 1, wc = w & 1;                 // wave -> 64x32 sub-tile
    int r = l & 15, kg = l >> 4;
    f32x4 acc[4][2] = {};

    // staging: slot s (16B): row = s>>3, col8 = s&7; source pre-swizzled
    int sA0 = 0*256 + w*64 + l;
    int sA1 = 1*256 + w*64 + l;
    int sA2 = 2*256 + w*64 + l;
    int sA3 = 3*256 + w*64 + l;
    int sB0 = 0*256 + w*64 + l;
    int sB1 = 1*256 + w*64 + l;
    const bf16* gA0 = A + (size_t)(m0 + (sA0>>3))*K1_ + ((sA0&7) ^ ((sA0>>3)&7))*8;
    const bf16* gA1 = A + (size_t)(m0 + (sA1>>3))*K1_ + ((sA1&7) ^ ((sA1>>3)&7))*8;
    const bf16* gA2 = A + (size_t)(m0 + (sA2>>3))*K1_ + ((sA2&7) ^ ((sA2>>3)&7))*8;
    const bf16* gA3 = A + (size_t)(m0 + (sA3>>3))*K1_ + ((sA3&7) ^ ((sA3>>3)&7))*8;
    const bf16* gB0 = Bw + (size_t)(n0 + (sB0>>3))*K1_ + ((sB0&7) ^ ((sB0>>3)&7))*8;
    const bf16* gB1 = Bw + (size_t)(n0 + (sB1>>3))*K1_ + ((sB1&7) ^ ((sB1>>3)&7))*8;
    bf16* lA0 = &As[(0*256 + w*64)*8];
    bf16* lA1 = &As[(1*256 + w*64)*8];
    bf16* lA2 = &As[(2*256 + w*64)*8];
    bf16* lA3 = &As[(3*256 + w*64)*8];
    bf16* lB0 = &Bs[(0*256 + w*64)*8];
    bf16* lB1 = &Bs[(1*256 + w*64)*8];

    for(int k0 = 0; k0 < K1_; k0 += 64){
        GLD16(gA0 + k0, lA0);
        GLD16(gA1 + k0, lA1);
        GLD16(gA2 + k0, lA2);
        GLD16(gA3 + k0, lA3);
        GLD16(gB0 + k0, lB0);
        GLD16(gB1 + k0, lB1);
        __syncthreads();
        short8 af[2][4], bfr[2][2];
        #pragma unroll
        for(int kh = 0; kh < 2; ++kh){
            #pragma unroll
            for(int m = 0; m < 4; ++m){
                int row = wr*64 + m*16 + r;
                int e = (row*64 + kh*32 + kg*8) ^ ((r & 7) << 3);
                af[kh][m] = *(const short8*)&As[e];
            }
            #pragma unroll
            for(int n = 0; n < 2; ++n){
                int row = wc*32 + n*16 + r;
                int e = (row*64 + kh*32 + kg*8) ^ ((r & 7) << 3);
                bfr[kh][n] = *(const short8*)&Bs[e];
            }
        }
        #pragma unroll
        for(int kh = 0; kh < 2; ++kh)
            #pragma unroll
            for(int m = 0; m < 4; ++m)
                #pragma unroll
                for(int n = 0; n < 2; ++n)
                    acc[m][n] = __builtin_amdgcn_mfma_f32_16x16x32_bf16(
                                    af[kh][m], bfr[kh][n], acc[m][n], 0, 0, 0);
        __syncthreads();
    }
    // C/D layout: col = lane&15, row = (lane>>4)*4 + i   [m89]
    #pragma unroll
    for(int m = 0; m < 4; ++m){
        int rowb = m0 + wr*64 + m*16 + kg*4;
        #pragma unroll
        for(int n = 0; n < 2; ++n){
            int col = n0 + wc*32 + n*16 + r;
            float bv = bias[col];
            #pragma unroll
            for(int i = 0; i < 4; ++i)
                C[(size_t)(rowb + i)*D4_ + col] = acc[m][n][i] + bv;
        }
    }
}

// -------------------------------------- per-channel sum / sumsq over M rows
__global__ void k_stats(const float* __restrict__ X, int C, float* __restrict__ ST){
    int r0 = blockIdx.x * 32;
    int tid = threadIdx.x;
    for(int c = tid; c < C; c += 256){
        float s = 0.f, q = 0.f;
        for(int r = 0; r < 32; ++r){
            float v = X[(size_t)(r0 + r)*C + c];
            s += v;
            q = fmaf(v, v, q);
        }
        atomicAdd(&ST[c], s);
        atomicAdd(&ST[C + c], q);
    }
}

__global__ void k_bnfin(const float* __restrict__ ST, const float* __restrict__ g,
                        const float* __restrict__ bb, int C, float* __restrict__ P){
    int c = blockIdx.x * blockDim.x + threadIdx.x;
    if(c < C){
        float mu  = ST[c] * (1.0f / M_);
        float var = ST[C + c] * (1.0f / M_) - mu*mu;
        float sc  = g[c] * rsqrtf(var + 1e-5f);
        P[c]     = sc;
        P[C + c] = bb[c] - mu*sc;
    }
}

// ------- y2 = gelu(BN1(y1)) @ W2^T + b2 ; MFMA 64x64, BK=64, fused BN+gelu on A
__global__ __launch_bounds__(256) void k_gemm2(const float* __restrict__ Y1,
        const float* __restrict__ P1, const bf16* __restrict__ W2b,
        const float* __restrict__ b2, float* __restrict__ Z){
    __shared__ __align__(16) bf16 As[64*64];     // 8 KB
    __shared__ __align__(16) bf16 Bs[64*64];     // 8 KB
    int m0 = blockIdx.x * 64, n0 = blockIdx.y * 64;
    int tid = threadIdx.x;
    int w = tid >> 6, l = tid & 63;
    int wr = w >> 1, wc = w & 1;                 // wave -> 32x32 sub-tile
    int r = l & 15, kg = l >> 4;
    f32x4 acc[2][2] = {};

    // B staging via GLD16, pre-swizzled source (same recipe as k_gemm1)
    int sB0 = 0*256 + w*64 + l;
    int sB1 = 1*256 + w*64 + l;
    const bf16* gB0 = W2b + (size_t)(n0 + (sB0>>3))*D4_ + ((sB0&7) ^ ((sB0>>3)&7))*8;
    const bf16* gB1 = W2b + (size_t)(n0 + (sB1>>3))*D4_ + ((sB1&7) ^ ((sB1>>3)&7))*8;
    bf16* lB0 = &Bs[(0*256 + w*64)*8];
    bf16* lB1 = &Bs[(1*256 + w*64)*8];

    // A transform: thread covers row=tid>>2, 16 k at (tid&3)*16
    int arow = tid >> 2;
    int akq  = (tid & 3) * 16;
    int k8a  = (tid & 3) * 2;
    int e0 = arow*64 + ((k8a+0) ^ (arow & 7))*8;
    int e1 = arow*64 + ((k8a+1) ^ (arow & 7))*8;

    for(int k0 = 0; k0 < D4_; k0 += 64){
        GLD16(gB0 + k0, lB0);
        GLD16(gB1 + k0, lB1);
        const float* ya = &Y1[(size_t)(m0 + arow)*D4_ + k0 + akq];
        const float* sc = &P1[k0 + akq];
        const float* sh = &P1[D4_ + k0 + akq];
        unsigned int pk[8];
        #pragma unroll
        for(int q = 0; q < 4; ++q){
            float4 y  = *(const float4*)&ya[q*4];
            float4 s4 = *(const float4*)&sc[q*4];
            float4 h4 = *(const float4*)&sh[q*4];
            float a0 = gelu_f(fmaf(y.x, s4.x, h4.x));
            float a1 = gelu_f(fmaf(y.y, s4.y, h4.y));
            float a2 = gelu_f(fmaf(y.z, s4.z, h4.z));
            float a3 = gelu_f(fmaf(y.w, s4.w, h4.w));
            pk[q*2+0] = (unsigned)bf16_bits(a0) | ((unsigned)bf16_bits(a1) << 16);
            pk[q*2+1] = (unsigned)bf16_bits(a2) | ((unsigned)bf16_bits(a3) << 16);
        }
        uint4 wA0 = {pk[0], pk[1], pk[2], pk[3]};
        uint4 wA1 = {pk[4], pk[5], pk[6], pk[7]};
        *(uint4*)&As[e0] = wA0;
        *(uint4*)&As[e1] = wA1;
        __syncthreads();             // drains vmcnt (GLD16) + lgkm (ds_write)
        short8 af[2][2], bfr[2][2];
        #pragma unroll
        for(int kh = 0; kh < 2; ++kh){
            #pragma unroll
            for(int m = 0; m < 2; ++m){
                int row = wr*32 + m*16 + r;
                int e = (row*64 + kh*32 + kg*8) ^ ((r & 7) << 3);
                af[kh][m] = *(const short8*)&As[e];
            }
            #pragma unroll
            for(int n = 0; n < 2; ++n){
                int row = wc*32 + n*16 + r;
                int e = (row*64 + kh*32 + kg*8) ^ ((r & 7) << 3);
                bfr[kh][n] = *(const short8*)&Bs[e];
            }
        }
        #pragma unroll
        for(int kh = 0; kh < 2; ++kh)
            #pragma unroll
            for(int m = 0; m < 2; ++m)
                #pragma unroll
                for(int n = 0; n < 2; ++n)
                    acc[m][n] = __builtin_amdgcn_mfma_f32_16x16x32_bf16(
                                    af[kh][m], bfr[kh][n], acc[m][n], 0, 0, 0);
        __syncthreads();
    }
    #pragma unroll
    for(int m = 0; m < 2; ++m){
        int rowb = m0 + wr*32 + m*16 + kg*4;
        #pragma unroll
        for(int n = 0; n < 2; ++n){
            int col = n0 + wc*32 + n*16 + r;
            float bv = b2[col];
            #pragma unroll
            for(int i = 0; i < 4; ++i)
                Z[(size_t)(rowb + i)*D_ + col] = acc[m][n][i] + bv;
        }
    }
}

// ------- z = gelu(BN2(y2)); LN over d; out[b,o,t] = z + zn (t-contig float4)
__global__ __launch_bounds__(256) void k_final(const float* __restrict__ Z,
        const float* __restrict__ P2, const float* __restrict__ lng,
        const float* __restrict__ lnb, float* __restrict__ out){
    __shared__ float s_z[64*129];
    __shared__ float s_mu[64];
    __shared__ float s_rs[64];
    int b  = blockIdx.x >> 2;
    int t0 = (blockIdx.x & 3) * 64;
    int tid = threadIdx.x;
    #pragma unroll
    for(int i = 0; i < 32; ++i){
        int idx = tid + i*256;
        int row = idx >> 7, col = idx & 127;
        float v = Z[(size_t)(b*T_ + t0 + row)*D_ + col];
        s_z[row*129 + col] = gelu_f(fmaf(v, P2[col], P2[D_ + col]));
    }
    __syncthreads();
    if(tid < 64){
        float s = 0.f;
        #pragma unroll
        for(int j = 0; j < D_; ++j) s += s_z[tid*129 + j];
        float mu = s * (1.0f / D_);
        float q = 0.f;
        #pragma unroll
        for(int j = 0; j < D_; ++j){
            float dv = s_z[tid*129 + j] - mu;
            q = fmaf(dv, dv, q);
        }
        s_mu[tid] = mu;
        s_rs[tid] = rsqrtf(q * (1.0f / D_) + 1e-5f);
    }
    __syncthreads();
    int o  = tid & 127;
    int th = tid >> 7;               // 0/1 -> t-half of the 64-row tile
    float g  = lng[o];
    float be = lnb[o];
    #pragma unroll
    for(int j4 = 0; j4 < 8; ++j4){
        float4 ov;
        #pragma unroll
        for(int q = 0; q < 4; ++q){
            int tt = th*32 + j4*4 + q;
            float z = s_z[tt*129 + o];
            float zn = fmaf((z - s_mu[tt]) * s_rs[tt], g, be);
            (&ov.x)[q] = z + zn;
        }
        *(float4*)&out[((size_t)(b*D_ + o))*T_ + t0 + th*32 + j4*4] = ov;
    }
}

extern "C" void kernel_launch(void* const* d_in, const int* in_sizes, int n_in,
                              void* d_out, int out_size, void* d_ws, size_t ws_size,
                              hipStream_t stream){
    const float* Xtemp   = (const float*)d_in[0];
    const float* Xtimes  = (const float*)d_in[1];
    const float* Xstatic = (const float*)d_in[2];
    const int*   mask    = (const int*)  d_in[3];
    const float* Wq      = (const float*)d_in[4];
    const float* Wk      = (const float*)d_in[5];
    const float* Wv      = (const float*)d_in[6];
    const float* tempW   = (const float*)d_in[7];
    const float* tempB   = (const float*)d_in[8];
    const float* embW    = (const float*)d_in[9];
    const float* embB    = (const float*)d_in[10];
    const float* W1      = (const float*)d_in[11];
    const float* b1      = (const float*)d_in[12];
    const float* bn1g    = (const float*)d_in[13];
    const float* bn1b    = (const float*)d_in[14];
    const float* W2      = (const float*)d_in[15];
    const float* b2      = (const float*)d_in[16];
    const float* bn2g    = (const float*)d_in[17];
    const float* bn2b    = (const float*)d_in[18];
    const float* lng     = (const float*)d_in[19];
    const float* lnb     = (const float*)d_in[20];
    float* out = (float*)d_out;

    float* w = (float*)d_ws;
    float* PE = w;  w += (size_t)M_ * D_;            // 1,048,576 f32
    float* CB = w;  w += (size_t)B_ * V_ * D_;       // 147,456
    float* cbP= w;  w += (size_t)B_ * 9 * D_ * 4;    // 147,456
    float* twP= w;  w += (size_t)9 * D_ * 4;         // 4,608
    float* H4 = w;  w += (size_t)B_ * V_ * D_;
    float* QS = w;  w += (size_t)B_ * V_ * D_;
    float* KS = w;  w += (size_t)B_ * V_ * D_;
    float* MV = w;  w += (size_t)B_ * V_ * D_;
    float* E  = w;  w += (size_t)B_ * 144 * 40;      // 184,320 (padded rows)
    float* QQ = w;  w += (size_t)M_ * 80;            // 655,360
    float* Y1 = w;  w += (size_t)M_ * D4_;           // 4,194,304
    float* Z1 = w;  w += (size_t)M_ * D_;            // 1,048,576
    float* ST1 = w; w += 1024;
    float* ST2 = w; w += 256;
    float* P1  = w; w += 1024;
    float* P2  = w; w += 256;
    bf16* V5  = (bf16*)w;                            // 75.5 MB
    bf16* W1b = V5 + (size_t)M_ * K1_;               // 4.7 MB
    bf16* W2b = W1b + (size_t)D4_ * K1_;             // 128 KB

    hipMemsetAsync(ST1, 0, (1024 + 256) * sizeof(float), stream);

    k_pe    <<<M_, D_, 0, stream>>>(Xtimes, Xtemp, mask, PE, QQ);
    k_cb    <<<B_*V_, D_, 0, stream>>>(Xstatic, embW, embB, tempB, CB, cbP);
    k_packtw<<<V_, D_, 0, stream>>>(tempW, twP);
    k_cast  <<<(D4_*K1_)/1024, 256, 0, stream>>>(W1, W1b);
    k_cast  <<<(D_*D4_)/1024, 256, 0, stream>>>(W2, W2b);
    k_h4    <<<B_*V_, 256, 0, stream>>>(Xtemp, mask, PE, tempW, CB, H4);
    k_qkv   <<<B_*V_, D_, 0, stream>>>(H4, Wq, Wk, Wv, QS, KS, MV);
    k_attE  <<<B_*H_*V_, 64, 0, stream>>>(QS, KS, E);
    k_v5    <<<M_, 256, 0, stream>>>(QQ, E, twP, cbP, MV, PE, V5);
    k_gemm1 <<<512, 256, 0, stream>>>(V5, W1b, b1, Y1);
    k_stats <<<M_/32, 256, 0, stream>>>(Y1, D4_, ST1);
    k_bnfin <<<2, 256, 0, stream>>>(ST1, bn1g, bn1b, D4_, P1);
    k_gemm2 <<<dim3(M_/64, D_/64), 256, 0, stream>>>(Y1, P1, W2b, b2, Z1);
    k_stats <<<M_/32, 256, 0, stream>>>(Z1, D_, ST2);
    k_bnfin <<<1, 128, 0, stream>>>(ST2, bn2g, bn2b, D_, P2);
    k_final <<<B_*(T_/64), 256, 0, stream>>>(Z1, P2, lng, lnb, out);
}

// Round 12
// 390.320 us; speedup vs baseline: 1.9880x; 1.0000x over previous
//
#include <hip/hip_runtime.h>
#include <hip/hip_bf16.h>
#include <math.h>

#define T_  256
#define B_  32
#define V_  36
#define D_  128
#define H_  4
#define DK_ 32
#define S_  16
#define D4_ 512
#define K1_ 4608   // V_*D_
#define M_  8192   // B_*T_

typedef __hip_bfloat16 bf16;
typedef __attribute__((ext_vector_type(8))) short short8;
typedef __attribute__((ext_vector_type(4))) float f32x4;

__device__ __forceinline__ float gelu_f(float x){
    return 0.5f * x * (1.0f + erff(x * 0.70710678118654752f));
}

__device__ __forceinline__ float dot4(float4 a, float4 b){
    return fmaf(a.x, b.x, fmaf(a.y, b.y, fmaf(a.z, b.z, a.w * b.w)));
}

__device__ __forceinline__ unsigned short bf16_bits(float x){
    bf16 h = __float2bfloat16(x);
    return *reinterpret_cast<unsigned short*>(&h);
}

#define GLD16(g, l) __builtin_amdgcn_global_load_lds( \
    (const __attribute__((address_space(1))) void*)(g), \
    (__attribute__((address_space(3))) void*)(l), 16, 0, 0)

// ------------------- PE[(b,t),dd]  +  QQ[bt][80] = {q1=mk*xt | q0=mk} w/ fallback
__global__ void k_pe(const float* __restrict__ Xtimes, const float* __restrict__ Xtemp,
                     const int* __restrict__ mask, float* __restrict__ PE,
                     float* __restrict__ QQ){
    int bt = blockIdx.x;            // b*T_+t
    int b = bt >> 8, t = bt & 255;
    int tid = threadIdx.x;          // 0..127
    float x = Xtimes[t*B_ + b];
    int i = (tid < 64) ? tid : tid - 64;
    float sc = x * exp2f(-(float)i * (8.965784284662087f / 63.0f));
    PE[(size_t)bt*D_ + tid] = (tid < 64) ? sinf(sc) : cosf(sc);
    // wave 0 builds q1/q0
    if(tid < 64){
        float m = 0.f, xv = 0.f;
        if(tid < V_){
            m  = (float)mask[(t*B_ + b)*V_ + tid];
            xv = Xtemp[(t*B_ + b)*V_ + tid];
        }
        float s = m;
        #pragma unroll
        for(int off = 32; off > 0; off >>= 1) s += __shfl_xor(s, off);
        if(tid < V_){
            float q0 = (s > 0.f) ? m : 1.f;          // all-masked fallback
            float q1 = (s > 0.f) ? m*xv : xv;
            QQ[(size_t)bt*80 + tid]      = q1;
            QQ[(size_t)bt*80 + 40 + tid] = q0;
        }
    }
}

// ---------------- CB[b,v,dd] (orig) + cbP[b][u4][dd][4] (packed for k_v5)
__global__ void k_cb(const float* __restrict__ Xstatic, const float* __restrict__ embW,
                     const float* __restrict__ embB, const float* __restrict__ tempB,
                     float* __restrict__ CB, float* __restrict__ cbP){
    int bv = blockIdx.x;            // b*V_+v
    int b = bv / V_, v = bv - (bv / V_) * V_;
    int dd = threadIdx.x;
    int c = v*D_ + dd;
    float acc = tempB[c] + embB[c];
    #pragma unroll
    for(int s = 0; s < S_; ++s) acc = fmaf(Xstatic[b*S_+s], embW[s*K1_ + c], acc);
    CB[(size_t)bv*D_ + dd] = acc;
    cbP[(((size_t)b*9 + (v >> 2))*D_ + dd)*4 + (v & 3)] = acc;
}

// ---------------------------------------------- twP[u4][dd][4] packed temp_w
__global__ void k_packtw(const float* __restrict__ tempW, float* __restrict__ twP){
    int v = blockIdx.x, dd = threadIdx.x;
    twP[(((v >> 2))*D_ + dd)*4 + (v & 3)] = tempW[v*D_ + dd];
}

// ---------------- per (b,v): sm, sx, sp; H4 = (sx*temp_w + sm*CB + sp)/(sm+1)
__global__ void k_h4(const float* __restrict__ Xtemp, const int* __restrict__ mask,
                     const float* __restrict__ PE, const float* __restrict__ tempW,
                     const float* __restrict__ CB, float* __restrict__ H4){
    __shared__ float s_m[T_];
    __shared__ float s_r0[256];
    __shared__ float s_r1[256];
    __shared__ float s_p[2][D_];
    int bv = blockIdx.x;
    int b = bv / V_, v = bv - (bv / V_) * V_;
    int tid = threadIdx.x;          // = t
    float mval = (float)mask[(tid*B_ + b)*V_ + v];
    float xval = Xtemp[(tid*B_ + b)*V_ + v];
    s_m[tid]  = mval;
    s_r0[tid] = mval;
    s_r1[tid] = mval * xval;
    __syncthreads();
    for(int off = 128; off > 0; off >>= 1){
        if(tid < off){ s_r0[tid] += s_r0[tid+off]; s_r1[tid] += s_r1[tid+off]; }
        __syncthreads();
    }
    float sm = s_r0[0], sx = s_r1[0];
    int dd = tid & 127, half = tid >> 7;
    float sp = 0.f;
    for(int tt = half*128; tt < half*128 + 128; ++tt)
        sp = fmaf(s_m[tt], PE[(size_t)(b*T_ + tt)*D_ + dd], sp);
    s_p[half][dd] = sp;
    __syncthreads();
    if(tid < D_){
        float spv = s_p[0][tid] + s_p[1][tid];
        float h2 = fmaf(sx, tempW[v*D_ + tid], fmaf(sm, CB[(size_t)bv*D_ + tid], spv));
        H4[(size_t)bv*D_ + tid] = h2 / (sm + 1.0f);
    }
}

// ---------------------------------------------- q,k (scaled), mean_v per (b,v)
__global__ void k_qkv(const float* __restrict__ H4, const float* __restrict__ Wq,
                      const float* __restrict__ Wk, const float* __restrict__ Wv,
                      float* __restrict__ QS, float* __restrict__ KS, float* __restrict__ MV){
    __shared__ float s_h[D_];
    int bv = blockIdx.x;
    int o = threadIdx.x;
    s_h[o] = H4[(size_t)bv*D_ + o];
    __syncthreads();
    float aq = 0.f, ak = 0.f, av = 0.f;
    #pragma unroll 8
    for(int kk = 0; kk < D_; ++kk){
        float hv = s_h[kk];
        aq = fmaf(hv, Wq[kk*D_ + o], aq);
        ak = fmaf(hv, Wk[kk*D_ + o], ak);
        av = fmaf(hv, Wv[kk*D_ + o], av);
    }
    const float scale = 0.17677669529663687f;  // 1/sqrt(32)
    QS[(size_t)bv*D_ + o] = aq * scale;
    KS[(size_t)bv*D_ + o] = ak * scale;
    MV[(size_t)bv*D_ + o] = av;
}

// --------------- E[b,hv][u] (row stride 40): exp(A - rowmax(A over all u))
__global__ void k_attE(const float* __restrict__ QS, const float* __restrict__ KS,
                       float* __restrict__ E){
    int id = blockIdx.x;             // b*144 + hh*36 + v
    int v  = id % V_;
    int bh = id / V_;
    int hh = bh & 3, b = bh >> 2;
    int u = threadIdx.x;             // 0..63
    __shared__ float s_q[DK_];
    if(u < DK_) s_q[u] = QS[(size_t)(b*V_ + v)*D_ + hh*DK_ + u];
    __syncthreads();
    float a = -INFINITY;
    if(u < V_){
        a = 0.f;
        const float* kp = &KS[(size_t)(b*V_ + u)*D_ + hh*DK_];
        #pragma unroll
        for(int kk = 0; kk < DK_; ++kk) a = fmaf(s_q[kk], kp[kk], a);
    }
    float m = a;
    for(int off = 32; off > 0; off >>= 1) m = fmaxf(m, __shfl_xor(m, off));
    if(u < V_) E[(size_t)id*40 + u] = expf(a - m);
}

// ---------------- k_v5 v4: block = one (b,t). E pre-normalized by den in LDS.
// thread = (vq:4, hh:4, j:16) -> dd0=hh*32+j, dd1=dd0+16, v = vq*9+vv
// out[bt, dd*36+v] = sum_u E'[hv,u]*(q1[u]*tw[u,dd]+q0[u]*cb[u,dd]) + MV + PE
__global__ __launch_bounds__(256) void k_v5(const float* __restrict__ QQ,
        const float* __restrict__ Eg, const float* __restrict__ twP,
        const float* __restrict__ cbP, const float* __restrict__ MV,
        const float* __restrict__ PE, bf16* __restrict__ V5){
    __shared__ float s_E[4*1300];     // [hh] base stride 1300 dw (20 mod 32)
    int bt = blockIdx.x;
    int b = bt >> 8;
    int tid = threadIdx.x;
    int vq = tid >> 6, hh = (tid >> 4) & 3, j = tid & 15;
    int dd0 = hh*32 + j, dd1 = dd0 + 16;
    const float* qq = &QQ[(size_t)bt*80];

    for(int i = tid; i < 144*9; i += 256){
        int hv = i / 9, u4 = i - hv*9;
        int hq = hv / 36, vr = hv - hq*36;
        float4 e = *(const float4*)&Eg[((size_t)b*144 + hv)*40 + u4*4];
        *(float4*)&s_E[hq*1300 + (u4*36 + vr)*4] = e;
    }
    __syncthreads();
    // fold 1/den into E: den[hv] = sum_u E*q0 (per-block scalar per hv)
    if(tid < 144){
        int hq = tid / 36, vr = tid - hq*36;
        float den = 0.f;
        #pragma unroll
        for(int u4 = 0; u4 < 9; ++u4){
            float4 e  = *(const float4*)&s_E[hq*1300 + (u4*36 + vr)*4];
            float4 q0 = *(const float4*)&qq[40 + u4*4];
            den += dot4(e, q0);
        }
        float rd = 1.0f / den;
        #pragma unroll
        for(int u4 = 0; u4 < 9; ++u4){
            float* ep = &s_E[hq*1300 + (u4*36 + vr)*4];
            float4 e = *(const float4*)ep;
            e.x *= rd; e.y *= rd; e.z *= rd; e.w *= rd;
            *(float4*)ep = e;
        }
    }
    __syncthreads();

    float acc0[9] = {}, acc1[9] = {};
    #pragma unroll 1                  // keep register pressure flat
    for(int u4 = 0; u4 < 9; ++u4){
        float4 q1 = *(const float4*)&qq[u4*4];
        float4 q0 = *(const float4*)&qq[40 + u4*4];
        float4 tw0 = *(const float4*)&twP[(u4*D_ + dd0)*4];
        float4 tw1 = *(const float4*)&twP[(u4*D_ + dd1)*4];
        float4 cb0 = *(const float4*)&cbP[(((size_t)b*9 + u4)*D_ + dd0)*4];
        float4 cb1 = *(const float4*)&cbP[(((size_t)b*9 + u4)*D_ + dd1)*4];
        float4 w0, w1;
        w0.x = fmaf(q1.x, tw0.x, q0.x*cb0.x); w0.y = fmaf(q1.y, tw0.y, q0.y*cb0.y);
        w0.z = fmaf(q1.z, tw0.z, q0.z*cb0.z); w0.w = fmaf(q1.w, tw0.w, q0.w*cb0.w);
        w1.x = fmaf(q1.x, tw1.x, q0.x*cb1.x); w1.y = fmaf(q1.y, tw1.y, q0.y*cb1.y);
        w1.z = fmaf(q1.z, tw1.z, q0.z*cb1.z); w1.w = fmaf(q1.w, tw1.w, q0.w*cb1.w);
        const float* eb = &s_E[hh*1300 + (u4*36 + vq*9)*4];
        #pragma unroll
        for(int vv = 0; vv < 9; ++vv){
            float4 e = *(const float4*)&eb[vv*4];
            acc0[vv] += dot4(e, w0);
            acc1[vv] += dot4(e, w1);
        }
    }
    float pe0 = PE[(size_t)bt*D_ + dd0];
    float pe1 = PE[(size_t)bt*D_ + dd1];
    bf16* op0 = V5 + (size_t)bt*K1_ + dd0*V_ + vq*9;
    bf16* op1 = V5 + (size_t)bt*K1_ + dd1*V_ + vq*9;
    #pragma unroll
    for(int vv = 0; vv < 9; ++vv){
        float m0v = MV[((size_t)b*V_ + vq*9 + vv)*D_ + dd0];
        float m1v = MV[((size_t)b*V_ + vq*9 + vv)*D_ + dd1];
        op0[vv] = __float2bfloat16(acc0[vv] + m0v + pe0);
        op1[vv] = __float2bfloat16(acc1[vv] + m1v + pe1);
    }
}

// ------------------------------------------- f32 -> bf16 (4 elems/thread)
__global__ void k_cast(const float* __restrict__ src, bf16* __restrict__ dst){
    int i = (blockIdx.x*256 + threadIdx.x)*4;
    float4 v = *(const float4*)&src[i];
    dst[i+0] = __float2bfloat16(v.x);
    dst[i+1] = __float2bfloat16(v.y);
    dst[i+2] = __float2bfloat16(v.z);
    dst[i+3] = __float2bfloat16(v.w);
}

// ---------------- y1 = V5 @ W1^T + b1 ; MFMA 128x64 tile, BK=64, XOR-swizzled LDS
__global__ __launch_bounds__(256) void k_gemm1(const bf16* __restrict__ A,
        const bf16* __restrict__ Bw, const float* __restrict__ bias,
        float* __restrict__ C){
    __shared__ __align__(16) bf16 As[128*64];    // 16 KB
    __shared__ __align__(16) bf16 Bs[64*64];     // 8 KB
    int bid = blockIdx.x;
    int L = (bid & 7)*64 + (bid >> 3);           // XCD-chunk swizzle (512%8==0)
    int nb = L & 7, mb = L >> 3;
    int m0 = mb * 128, n0 = nb * 64;
    int tid = threadIdx.x;
    int w = tid >> 6, l = tid & 63;
    int wr = w >> 1, wc = w & 1;                 // wave -> 64x32 sub-tile
    int r = l & 15, kg = l >> 4;
    f32x4 acc[4][2] = {};

    // staging: slot s (16B): row = s>>3, col8 = s&7; source pre-swizzled
    int sA0 = 0*256 + w*64 + l;
    int sA1 = 1*256 + w*64 + l;
    int sA2 = 2*256 + w*64 + l;
    int sA3 = 3*256 + w*64 + l;
    int sB0 = 0*256 + w*64 + l;
    int sB1 = 1*256 + w*64 + l;
    const bf16* gA0 = A + (size_t)(m0 + (sA0>>3))*K1_ + ((sA0&7) ^ ((sA0>>3)&7))*8;
    const bf16* gA1 = A + (size_t)(m0 + (sA1>>3))*K1_ + ((sA1&7) ^ ((sA1>>3)&7))*8;
    const bf16* gA2 = A + (size_t)(m0 + (sA2>>3))*K1_ + ((sA2&7) ^ ((sA2>>3)&7))*8;
    const bf16* gA3 = A + (size_t)(m0 + (sA3>>3))*K1_ + ((sA3&7) ^ ((sA3>>3)&7))*8;
    const bf16* gB0 = Bw + (size_t)(n0 + (sB0>>3))*K1_ + ((sB0&7) ^ ((sB0>>3)&7))*8;
    const bf16* gB1 = Bw + (size_t)(n0 + (sB1>>3))*K1_ + ((sB1&7) ^ ((sB1>>3)&7))*8;
    bf16* lA0 = &As[(0*256 + w*64)*8];
    bf16* lA1 = &As[(1*256 + w*64)*8];
    bf16* lA2 = &As[(2*256 + w*64)*8];
    bf16* lA3 = &As[(3*256 + w*64)*8];
    bf16* lB0 = &Bs[(0*256 + w*64)*8];
    bf16* lB1 = &Bs[(1*256 + w*64)*8];

    for(int k0 = 0; k0 < K1_; k0 += 64){
        GLD16(gA0 + k0, lA0);
        GLD16(gA1 + k0, lA1);
        GLD16(gA2 + k0, lA2);
        GLD16(gA3 + k0, lA3);
        GLD16(gB0 + k0, lB0);
        GLD16(gB1 + k0, lB1);
        __syncthreads();
        short8 af[2][4], bfr[2][2];
        #pragma unroll
        for(int kh = 0; kh < 2; ++kh){
            #pragma unroll
            for(int m = 0; m < 4; ++m){
                int row = wr*64 + m*16 + r;
                int e = (row*64 + kh*32 + kg*8) ^ ((r & 7) << 3);
                af[kh][m] = *(const short8*)&As[e];
            }
            #pragma unroll
            for(int n = 0; n < 2; ++n){
                int row = wc*32 + n*16 + r;
                int e = (row*64 + kh*32 + kg*8) ^ ((r & 7) << 3);
                bfr[kh][n] = *(const short8*)&Bs[e];
            }
        }
        #pragma unroll
        for(int kh = 0; kh < 2; ++kh)
            #pragma unroll
            for(int m = 0; m < 4; ++m)
                #pragma unroll
                for(int n = 0; n < 2; ++n)
                    acc[m][n] = __builtin_amdgcn_mfma_f32_16x16x32_bf16(
                                    af[kh][m], bfr[kh][n], acc[m][n], 0, 0, 0);
        __syncthreads();
    }
    // C/D layout: col = lane&15, row = (lane>>4)*4 + i   [m89]
    #pragma unroll
    for(int m = 0; m < 4; ++m){
        int rowb = m0 + wr*64 + m*16 + kg*4;
        #pragma unroll
        for(int n = 0; n < 2; ++n){
            int col = n0 + wc*32 + n*16 + r;
            float bv = bias[col];
            #pragma unroll
            for(int i = 0; i < 4; ++i)
                C[(size_t)(rowb + i)*D4_ + col] = acc[m][n][i] + bv;
        }
    }
}

// -------------------------------------- per-channel sum / sumsq over M rows
__global__ void k_stats(const float* __restrict__ X, int C, float* __restrict__ ST){
    int r0 = blockIdx.x * 32;
    int tid = threadIdx.x;
    for(int c = tid; c < C; c += 256){
        float s = 0.f, q = 0.f;
        for(int r = 0; r < 32; ++r){
            float v = X[(size_t)(r0 + r)*C + c];
            s += v;
            q = fmaf(v, v, q);
        }
        atomicAdd(&ST[c], s);
        atomicAdd(&ST[C + c], q);
    }
}

__global__ void k_bnfin(const float* __restrict__ ST, const float* __restrict__ g,
                        const float* __restrict__ bb, int C, float* __restrict__ P){
    int c = blockIdx.x * blockDim.x + threadIdx.x;
    if(c < C){
        float mu  = ST[c] * (1.0f / M_);
        float var = ST[C + c] * (1.0f / M_) - mu*mu;
        float sc  = g[c] * rsqrtf(var + 1e-5f);
        P[c]     = sc;
        P[C + c] = bb[c] - mu*sc;
    }
}

// ------- y2 = gelu(BN1(y1)) @ W2^T + b2 ; MFMA 64x64, BK=64, fused BN+gelu on A
__global__ __launch_bounds__(256) void k_gemm2(const float* __restrict__ Y1,
        const float* __restrict__ P1, const bf16* __restrict__ W2b,
        const float* __restrict__ b2, float* __restrict__ Z){
    __shared__ __align__(16) bf16 As[64*64];     // 8 KB
    __shared__ __align__(16) bf16 Bs[64*64];     // 8 KB
    int m0 = blockIdx.x * 64, n0 = blockIdx.y * 64;
    int tid = threadIdx.x;
    int w = tid >> 6, l = tid & 63;
    int wr = w >> 1, wc = w & 1;                 // wave -> 32x32 sub-tile
    int r = l & 15, kg = l >> 4;
    f32x4 acc[2][2] = {};

    // B staging via GLD16, pre-swizzled source (same recipe as k_gemm1)
    int sB0 = 0*256 + w*64 + l;
    int sB1 = 1*256 + w*64 + l;
    const bf16* gB0 = W2b + (size_t)(n0 + (sB0>>3))*D4_ + ((sB0&7) ^ ((sB0>>3)&7))*8;
    const bf16* gB1 = W2b + (size_t)(n0 + (sB1>>3))*D4_ + ((sB1&7) ^ ((sB1>>3)&7))*8;
    bf16* lB0 = &Bs[(0*256 + w*64)*8];
    bf16* lB1 = &Bs[(1*256 + w*64)*8];

    // A transform: thread covers row=tid>>2, 16 k at (tid&3)*16
    int arow = tid >> 2;
    int akq  = (tid & 3) * 16;
    int k8a  = (tid & 3) * 2;
    int e0 = arow*64 + ((k8a+0) ^ (arow & 7))*8;
    int e1 = arow*64 + ((k8a+1) ^ (arow & 7))*8;

    for(int k0 = 0; k0 < D4_; k0 += 64){
        GLD16(gB0 + k0, lB0);
        GLD16(gB1 + k0, lB1);
        const float* ya = &Y1[(size_t)(m0 + arow)*D4_ + k0 + akq];
        const float* sc = &P1[k0 + akq];
        const float* sh = &P1[D4_ + k0 + akq];
        unsigned int pk[8];
        #pragma unroll
        for(int q = 0; q < 4; ++q){
            float4 y  = *(const float4*)&ya[q*4];
            float4 s4 = *(const float4*)&sc[q*4];
            float4 h4 = *(const float4*)&sh[q*4];
            float a0 = gelu_f(fmaf(y.x, s4.x, h4.x));
            float a1 = gelu_f(fmaf(y.y, s4.y, h4.y));
            float a2 = gelu_f(fmaf(y.z, s4.z, h4.z));
            float a3 = gelu_f(fmaf(y.w, s4.w, h4.w));
            pk[q*2+0] = (unsigned)bf16_bits(a0) | ((unsigned)bf16_bits(a1) << 16);
            pk[q*2+1] = (unsigned)bf16_bits(a2) | ((unsigned)bf16_bits(a3) << 16);
        }
        uint4 wA0 = {pk[0], pk[1], pk[2], pk[3]};
        uint4 wA1 = {pk[4], pk[5], pk[6], pk[7]};
        *(uint4*)&As[e0] = wA0;
        *(uint4*)&As[e1] = wA1;
        __syncthreads();             // drains vmcnt (GLD16) + lgkm (ds_write)
        short8 af[2][2], bfr[2][2];
        #pragma unroll
        for(int kh = 0; kh < 2; ++kh){
            #pragma unroll
            for(int m = 0; m < 2; ++m){
                int row = wr*32 + m*16 + r;
                int e = (row*64 + kh*32 + kg*8) ^ ((r & 7) << 3);
                af[kh][m] = *(const short8*)&As[e];
            }
            #pragma unroll
            for(int n = 0; n < 2; ++n){
                int row = wc*32 + n*16 + r;
                int e = (row*64 + kh*32 + kg*8) ^ ((r & 7) << 3);
                bfr[kh][n] = *(const short8*)&Bs[e];
            }
        }
        #pragma unroll
        for(int kh = 0; kh < 2; ++kh)
            #pragma unroll
            for(int m = 0; m < 2; ++m)
                #pragma unroll
                for(int n = 0; n < 2; ++n)
                    acc[m][n] = __builtin_amdgcn_mfma_f32_16x16x32_bf16(
                                    af[kh][m], bfr[kh][n], acc[m][n], 0, 0, 0);
        __syncthreads();
    }
    #pragma unroll
    for(int m = 0; m < 2; ++m){
        int rowb = m0 + wr*32 + m*16 + kg*4;
        #pragma unroll
        for(int n = 0; n < 2; ++n){
            int col = n0 + wc*32 + n*16 + r;
            float bv = b2[col];
            #pragma unroll
            for(int i = 0; i < 4; ++i)
                Z[(size_t)(rowb + i)*D_ + col] = acc[m][n][i] + bv;
        }
    }
}

// ------- z = gelu(BN2(y2)); LN over d; out[b,o,t] = z + zn (t-contig float4)
__global__ __launch_bounds__(256) void k_final(const float* __restrict__ Z,
        const float* __restrict__ P2, const float* __restrict__ lng,
        const float* __restrict__ lnb, float* __restrict__ out){
    __shared__ float s_z[64*129];
    __shared__ float s_mu[64];
    __shared__ float s_rs[64];
    int b  = blockIdx.x >> 2;
    int t0 = (blockIdx.x & 3) * 64;
    int tid = threadIdx.x;
    #pragma unroll
    for(int i = 0; i < 32; ++i){
        int idx = tid + i*256;
        int row = idx >> 7, col = idx & 127;
        float v = Z[(size_t)(b*T_ + t0 + row)*D_ + col];
        s_z[row*129 + col] = gelu_f(fmaf(v, P2[col], P2[D_ + col]));
    }
    __syncthreads();
    if(tid < 64){
        float s = 0.f;
        #pragma unroll
        for(int j = 0; j < D_; ++j) s += s_z[tid*129 + j];
        float mu = s * (1.0f / D_);
        float q = 0.f;
        #pragma unroll
        for(int j = 0; j < D_; ++j){
            float dv = s_z[tid*129 + j] - mu;
            q = fmaf(dv, dv, q);
        }
        s_mu[tid] = mu;
        s_rs[tid] = rsqrtf(q * (1.0f / D_) + 1e-5f);
    }
    __syncthreads();
    int o  = tid & 127;
    int th = tid >> 7;               // 0/1 -> t-half of the 64-row tile
    float g  = lng[o];
    float be = lnb[o];
    #pragma unroll
    for(int j4 = 0; j4 < 8; ++j4){
        float4 ov;
        #pragma unroll
        for(int q = 0; q < 4; ++q){
            int tt = th*32 + j4*4 + q;
            float z = s_z[tt*129 + o];
            float zn = fmaf((z - s_mu[tt]) * s_rs[tt], g, be);
            (&ov.x)[q] = z + zn;
        }
        *(float4*)&out[((size_t)(b*D_ + o))*T_ + t0 + th*32 + j4*4] = ov;
    }
}

extern "C" void kernel_launch(void* const* d_in, const int* in_sizes, int n_in,
                              void* d_out, int out_size, void* d_ws, size_t ws_size,
                              hipStream_t stream){
    const float* Xtemp   = (const float*)d_in[0];
    const float* Xtimes  = (const float*)d_in[1];
    const float* Xstatic = (const float*)d_in[2];
    const int*   mask    = (const int*)  d_in[3];
    const float* Wq      = (const float*)d_in[4];
    const float* Wk      = (const float*)d_in[5];
    const float* Wv      = (const float*)d_in[6];
    const float* tempW   = (const float*)d_in[7];
    const float* tempB   = (const float*)d_in[8];
    const float* embW    = (const float*)d_in[9];
    const float* embB    = (const float*)d_in[10];
    const float* W1      = (const float*)d_in[11];
    const float* b1      = (const float*)d_in[12];
    const float* bn1g    = (const float*)d_in[13];
    const float* bn1b    = (const float*)d_in[14];
    const float* W2      = (const float*)d_in[15];
    const float* b2      = (const float*)d_in[16];
    const float* bn2g    = (const float*)d_in[17];
    const float* bn2b    = (const float*)d_in[18];
    const float* lng     = (const float*)d_in[19];
    const float* lnb     = (const float*)d_in[20];
    float* out = (float*)d_out;

    float* w = (float*)d_ws;
    float* PE = w;  w += (size_t)M_ * D_;            // 1,048,576 f32
    float* CB = w;  w += (size_t)B_ * V_ * D_;       // 147,456
    float* cbP= w;  w += (size_t)B_ * 9 * D_ * 4;    // 147,456
    float* twP= w;  w += (size_t)9 * D_ * 4;         // 4,608
    float* H4 = w;  w += (size_t)B_ * V_ * D_;
    float* QS = w;  w += (size_t)B_ * V_ * D_;
    float* KS = w;  w += (size_t)B_ * V_ * D_;
    float* MV = w;  w += (size_t)B_ * V_ * D_;
    float* E  = w;  w += (size_t)B_ * 144 * 40;      // 184,320 (padded rows)
    float* QQ = w;  w += (size_t)M_ * 80;            // 655,360
    float* Y1 = w;  w += (size_t)M_ * D4_;           // 4,194,304
    float* Z1 = w;  w += (size_t)M_ * D_;            // 1,048,576
    float* ST1 = w; w += 1024;
    float* ST2 = w; w += 256;
    float* P1  = w; w += 1024;
    float* P2  = w; w += 256;
    bf16* V5  = (bf16*)w;                            // 75.5 MB
    bf16* W1b = V5 + (size_t)M_ * K1_;               // 4.7 MB
    bf16* W2b = W1b + (size_t)D4_ * K1_;             // 128 KB

    hipMemsetAsync(ST1, 0, (1024 + 256) * sizeof(float), stream);

    k_pe    <<<M_, D_, 0, stream>>>(Xtimes, Xtemp, mask, PE, QQ);
    k_cb    <<<B_*V_, D_, 0, stream>>>(Xstatic, embW, embB, tempB, CB, cbP);
    k_packtw<<<V_, D_, 0, stream>>>(tempW, twP);
    k_cast  <<<(D4_*K1_)/1024, 256, 0, stream>>>(W1, W1b);
    k_cast  <<<(D_*D4_)/1024, 256, 0, stream>>>(W2, W2b);
    k_h4    <<<B_*V_, 256, 0, stream>>>(Xtemp, mask, PE, tempW, CB, H4);
    k_qkv   <<<B_*V_, D_, 0, stream>>>(H4, Wq, Wk, Wv, QS, KS, MV);
    k_attE  <<<B_*H_*V_, 64, 0, stream>>>(QS, KS, E);
    k_v5    <<<M_, 256, 0, stream>>>(QQ, E, twP, cbP, MV, PE, V5);
    k_gemm1 <<<512, 256, 0, stream>>>(V5, W1b, b1, Y1);
    k_stats <<<M_/32, 256, 0, stream>>>(Y1, D4_, ST1);
    k_bnfin <<<2, 256, 0, stream>>>(ST1, bn1g, bn1b, D4_, P1);
    k_gemm2 <<<dim3(M_/64, D_/64), 256, 0, stream>>>(Y1, P1, W2b, b2, Z1);
    k_stats <<<M_/32, 256, 0, stream>>>(Z1, D_, ST2);
    k_bnfin <<<1, 128, 0, stream>>>(ST2, bn2g, bn2b, D_, P2);
    k_final <<<B_*(T_/64), 256, 0, stream>>>(Z1, P2, lng, lnb, out);
}

// Round 13
// 382.026 us; speedup vs baseline: 2.0312x; 1.0217x over previous
//
#include <hip/hip_runtime.h>
#include <hip/hip_bf16.h>
#include <math.h>

#define T_  256
#define B_  32
#define V_  36
#define D_  128
#define H_  4
#define DK_ 32
#define S_  16
#define D4_ 512
#define K1_ 4608   // V_*D_
#define M_  8192   // B_*T_

typedef __hip_bfloat16 bf16;
typedef __attribute__((ext_vector_type(8))) short short8;
typedef __attribute__((ext_vector_type(4))) float f32x4;

__device__ __forceinline__ float gelu_f(float x){
    return 0.5f * x * (1.0f + erff(x * 0.70710678118654752f));
}

__device__ __forceinline__ float dot4(float4 a, float4 b){
    return fmaf(a.x, b.x, fmaf(a.y, b.y, fmaf(a.z, b.z, a.w * b.w)));
}

__device__ __forceinline__ unsigned short bf16_bits(float x){
    bf16 h = __float2bfloat16(x);
    return *reinterpret_cast<unsigned short*>(&h);
}

#define GLD16(g, l) __builtin_amdgcn_global_load_lds( \
    (const __attribute__((address_space(1))) void*)(g), \
    (__attribute__((address_space(3))) void*)(l), 16, 0, 0)

// ------------------- PE[(b,t),dd]  +  QQ[bt][80] = {q1=mk*xt | q0=mk} w/ fallback
__global__ void k_pe(const float* __restrict__ Xtimes, const float* __restrict__ Xtemp,
                     const int* __restrict__ mask, float* __restrict__ PE,
                     float* __restrict__ QQ){
    int bt = blockIdx.x;            // b*T_+t
    int b = bt >> 8, t = bt & 255;
    int tid = threadIdx.x;          // 0..127
    float x = Xtimes[t*B_ + b];
    int i = (tid < 64) ? tid : tid - 64;
    float sc = x * exp2f(-(float)i * (8.965784284662087f / 63.0f));
    PE[(size_t)bt*D_ + tid] = (tid < 64) ? sinf(sc) : cosf(sc);
    // wave 0 builds q1/q0
    if(tid < 64){
        float m = 0.f, xv = 0.f;
        if(tid < V_){
            m  = (float)mask[(t*B_ + b)*V_ + tid];
            xv = Xtemp[(t*B_ + b)*V_ + tid];
        }
        float s = m;
        #pragma unroll
        for(int off = 32; off > 0; off >>= 1) s += __shfl_xor(s, off);
        if(tid < V_){
            float q0 = (s > 0.f) ? m : 1.f;          // all-masked fallback
            float q1 = (s > 0.f) ? m*xv : xv;
            QQ[(size_t)bt*80 + tid]      = q1;
            QQ[(size_t)bt*80 + 40 + tid] = q0;
        }
    }
}

// ---------------- CB[b,v,dd] (orig) + cbP[b][u4][dd][4] (packed for k_v5)
__global__ void k_cb(const float* __restrict__ Xstatic, const float* __restrict__ embW,
                     const float* __restrict__ embB, const float* __restrict__ tempB,
                     float* __restrict__ CB, float* __restrict__ cbP){
    int bv = blockIdx.x;            // b*V_+v
    int b = bv / V_, v = bv - (bv / V_) * V_;
    int dd = threadIdx.x;
    int c = v*D_ + dd;
    float acc = tempB[c] + embB[c];
    #pragma unroll
    for(int s = 0; s < S_; ++s) acc = fmaf(Xstatic[b*S_+s], embW[s*K1_ + c], acc);
    CB[(size_t)bv*D_ + dd] = acc;
    cbP[(((size_t)b*9 + (v >> 2))*D_ + dd)*4 + (v & 3)] = acc;
}

// ---------------------------------------------- twP[u4][dd][4] packed temp_w
__global__ void k_packtw(const float* __restrict__ tempW, float* __restrict__ twP){
    int v = blockIdx.x, dd = threadIdx.x;
    twP[(((v >> 2))*D_ + dd)*4 + (v & 3)] = tempW[v*D_ + dd];
}

// ---------------- per (b,v): sm, sx, sp; H4 = (sx*temp_w + sm*CB + sp)/(sm+1)
__global__ void k_h4(const float* __restrict__ Xtemp, const int* __restrict__ mask,
                     const float* __restrict__ PE, const float* __restrict__ tempW,
                     const float* __restrict__ CB, float* __restrict__ H4){
    __shared__ float s_m[T_];
    __shared__ float s_r0[256];
    __shared__ float s_r1[256];
    __shared__ float s_p[2][D_];
    int bv = blockIdx.x;
    int b = bv / V_, v = bv - (bv / V_) * V_;
    int tid = threadIdx.x;          // = t
    float mval = (float)mask[(tid*B_ + b)*V_ + v];
    float xval = Xtemp[(tid*B_ + b)*V_ + v];
    s_m[tid]  = mval;
    s_r0[tid] = mval;
    s_r1[tid] = mval * xval;
    __syncthreads();
    for(int off = 128; off > 0; off >>= 1){
        if(tid < off){ s_r0[tid] += s_r0[tid+off]; s_r1[tid] += s_r1[tid+off]; }
        __syncthreads();
    }
    float sm = s_r0[0], sx = s_r1[0];
    int dd = tid & 127, half = tid >> 7;
    float sp = 0.f;
    for(int tt = half*128; tt < half*128 + 128; ++tt)
        sp = fmaf(s_m[tt], PE[(size_t)(b*T_ + tt)*D_ + dd], sp);
    s_p[half][dd] = sp;
    __syncthreads();
    if(tid < D_){
        float spv = s_p[0][tid] + s_p[1][tid];
        float h2 = fmaf(sx, tempW[v*D_ + tid], fmaf(sm, CB[(size_t)bv*D_ + tid], spv));
        H4[(size_t)bv*D_ + tid] = h2 / (sm + 1.0f);
    }
}

// ---------------------------------------------- q,k (scaled), mean_v per (b,v)
__global__ void k_qkv(const float* __restrict__ H4, const float* __restrict__ Wq,
                      const float* __restrict__ Wk, const float* __restrict__ Wv,
                      float* __restrict__ QS, float* __restrict__ KS, float* __restrict__ MV){
    __shared__ float s_h[D_];
    int bv = blockIdx.x;
    int o = threadIdx.x;
    s_h[o] = H4[(size_t)bv*D_ + o];
    __syncthreads();
    float aq = 0.f, ak = 0.f, av = 0.f;
    #pragma unroll 8
    for(int kk = 0; kk < D_; ++kk){
        float hv = s_h[kk];
        aq = fmaf(hv, Wq[kk*D_ + o], aq);
        ak = fmaf(hv, Wk[kk*D_ + o], ak);
        av = fmaf(hv, Wv[kk*D_ + o], av);
    }
    const float scale = 0.17677669529663687f;  // 1/sqrt(32)
    QS[(size_t)bv*D_ + o] = aq * scale;
    KS[(size_t)bv*D_ + o] = ak * scale;
    MV[(size_t)bv*D_ + o] = av;
}

// --------------- E[b,hv][u] (row stride 40): exp(A - rowmax(A over all u))
__global__ void k_attE(const float* __restrict__ QS, const float* __restrict__ KS,
                       float* __restrict__ E){
    int id = blockIdx.x;             // b*144 + hh*36 + v
    int v  = id % V_;
    int bh = id / V_;
    int hh = bh & 3, b = bh >> 2;
    int u = threadIdx.x;             // 0..63
    __shared__ float s_q[DK_];
    if(u < DK_) s_q[u] = QS[(size_t)(b*V_ + v)*D_ + hh*DK_ + u];
    __syncthreads();
    float a = -INFINITY;
    if(u < V_){
        a = 0.f;
        const float* kp = &KS[(size_t)(b*V_ + u)*D_ + hh*DK_];
        #pragma unroll
        for(int kk = 0; kk < DK_; ++kk) a = fmaf(s_q[kk], kp[kk], a);
    }
    float m = a;
    for(int off = 32; off > 0; off >>= 1) m = fmaxf(m, __shfl_xor(m, off));
    if(u < V_) E[(size_t)id*40 + u] = expf(a - m);
}

// --------------- RDEN[bt][144] = 1 / sum_u E[b,hv,u]*q0[bt,u]
__global__ void k_den(const float* __restrict__ Eg, const float* __restrict__ QQ,
                      float* __restrict__ RDEN){
    int bt = blockIdx.x;
    int b = bt >> 8;
    int hv = threadIdx.x;
    if(hv < 144){
        const float* q0 = &QQ[(size_t)bt*80 + 40];
        const float* ep = &Eg[((size_t)b*144 + hv)*40];
        float den = 0.f;
        #pragma unroll
        for(int u4 = 0; u4 < 9; ++u4)
            den += dot4(*(const float4*)&ep[u4*4], *(const float4*)&q0[u4*4]);
        RDEN[(size_t)bt*144 + hv] = 1.0f / den;
    }
}

// ---------------- k_v5 v5: block = (b, 8 t's). E staged ONCE per 8 t.
// thread = (vq:4, hh:4, j:16) -> dd0=hh*32+j, dd1=dd0+16, v = vq*9+vv
// V5 layout v-major: V5[bt][v*128+dd] = acc*rden + MV + PE  (coalesced stores)
__global__ __launch_bounds__(256) void k_v5(const float* __restrict__ QQ,
        const float* __restrict__ Eg, const float* __restrict__ twP,
        const float* __restrict__ cbP, const float* __restrict__ MV,
        const float* __restrict__ PE, const float* __restrict__ RDEN,
        bf16* __restrict__ V5){
    __shared__ float s_E[4*1300];     // [hh] base stride 1300 dw (20 mod 32)
    int blk = blockIdx.x;             // b*32 + tgrp
    int b = blk >> 5, tgrp = blk & 31;
    int bt0 = b*T_ + tgrp*8;
    int tid = threadIdx.x;
    int vq = tid >> 6, hh = (tid >> 4) & 3, j = tid & 15;
    int dd0 = hh*32 + j, dd1 = dd0 + 16;

    for(int i = tid; i < 144*9; i += 256){
        int hv = i / 9, u4 = i - hv*9;
        int hq = hv / 36, vr = hv - hq*36;
        float4 e = *(const float4*)&Eg[((size_t)b*144 + hv)*40 + u4*4];
        *(float4*)&s_E[hq*1300 + (u4*36 + vr)*4] = e;
    }
    __syncthreads();

    #pragma unroll 1
    for(int tg = 0; tg < 8; ++tg){
        int bt = bt0 + tg;
        const float* qq = &QQ[(size_t)bt*80];
        float acc0[9] = {}, acc1[9] = {};
        #pragma unroll 1              // keep register pressure flat
        for(int u4 = 0; u4 < 9; ++u4){
            float4 q1 = *(const float4*)&qq[u4*4];
            float4 q0 = *(const float4*)&qq[40 + u4*4];
            float4 tw0 = *(const float4*)&twP[(u4*D_ + dd0)*4];
            float4 tw1 = *(const float4*)&twP[(u4*D_ + dd1)*4];
            float4 cb0 = *(const float4*)&cbP[(((size_t)b*9 + u4)*D_ + dd0)*4];
            float4 cb1 = *(const float4*)&cbP[(((size_t)b*9 + u4)*D_ + dd1)*4];
            float4 w0, w1;
            w0.x = fmaf(q1.x, tw0.x, q0.x*cb0.x); w0.y = fmaf(q1.y, tw0.y, q0.y*cb0.y);
            w0.z = fmaf(q1.z, tw0.z, q0.z*cb0.z); w0.w = fmaf(q1.w, tw0.w, q0.w*cb0.w);
            w1.x = fmaf(q1.x, tw1.x, q0.x*cb1.x); w1.y = fmaf(q1.y, tw1.y, q0.y*cb1.y);
            w1.z = fmaf(q1.z, tw1.z, q0.z*cb1.z); w1.w = fmaf(q1.w, tw1.w, q0.w*cb1.w);
            const float* eb = &s_E[hh*1300 + (u4*36 + vq*9)*4];
            #pragma unroll
            for(int vv = 0; vv < 9; ++vv){
                float4 e = *(const float4*)&eb[vv*4];
                acc0[vv] += dot4(e, w0);
                acc1[vv] += dot4(e, w1);
            }
        }
        float pe0 = PE[(size_t)bt*D_ + dd0];
        float pe1 = PE[(size_t)bt*D_ + dd1];
        const float* rdp = &RDEN[(size_t)bt*144 + hh*36 + vq*9];
        bf16* op = V5 + (size_t)bt*K1_;
        #pragma unroll
        for(int vv = 0; vv < 9; ++vv){
            float rd = rdp[vv];
            float m0v = MV[((size_t)b*V_ + vq*9 + vv)*D_ + dd0];
            float m1v = MV[((size_t)b*V_ + vq*9 + vv)*D_ + dd1];
            op[(vq*9 + vv)*D_ + dd0] = __float2bfloat16(fmaf(acc0[vv], rd, m0v + pe0));
            op[(vq*9 + vv)*D_ + dd1] = __float2bfloat16(fmaf(acc1[vv], rd, m1v + pe1));
        }
    }
}

// ------------- W1 (f32, [o][dd*36+v]) -> bf16 [o][v*128+dd] (K-permuted cast)
__global__ void k_castw1(const float* __restrict__ src, bf16* __restrict__ dst){
    int i = blockIdx.x*256 + threadIdx.x;      // over 512*4608
    int o = i / K1_, c = i - o*K1_;
    int v = c >> 7, dd = c & 127;
    dst[i] = __float2bfloat16(src[(size_t)o*K1_ + dd*V_ + v]);
}

// ------------------------------------------- f32 -> bf16 (4 elems/thread)
__global__ void k_cast(const float* __restrict__ src, bf16* __restrict__ dst){
    int i = (blockIdx.x*256 + threadIdx.x)*4;
    float4 v = *(const float4*)&src[i];
    dst[i+0] = __float2bfloat16(v.x);
    dst[i+1] = __float2bfloat16(v.y);
    dst[i+2] = __float2bfloat16(v.z);
    dst[i+3] = __float2bfloat16(v.w);
}

// ---------------- y1 = V5 @ W1b^T + b1 ; MFMA 128x64 tile, BK=64, XOR-swizzled
// (A and W1b share the SAME permuted K order; result identical to reference)
__global__ __launch_bounds__(256) void k_gemm1(const bf16* __restrict__ A,
        const bf16* __restrict__ Bw, const float* __restrict__ bias,
        float* __restrict__ C){
    __shared__ __align__(16) bf16 As[128*64];    // 16 KB
    __shared__ __align__(16) bf16 Bs[64*64];     // 8 KB
    int bid = blockIdx.x;
    int L = (bid & 7)*64 + (bid >> 3);           // XCD-chunk swizzle (512%8==0)
    int nb = L & 7, mb = L >> 3;
    int m0 = mb * 128, n0 = nb * 64;
    int tid = threadIdx.x;
    int w = tid >> 6, l = tid & 63;
    int wr = w >> 1, wc = w & 1;                 // wave -> 64x32 sub-tile
    int r = l & 15, kg = l >> 4;
    f32x4 acc[4][2] = {};

    // staging: slot s (16B): row = s>>3, col8 = s&7; source pre-swizzled
    int sA0 = 0*256 + w*64 + l;
    int sA1 = 1*256 + w*64 + l;
    int sA2 = 2*256 + w*64 + l;
    int sA3 = 3*256 + w*64 + l;
    int sB0 = 0*256 + w*64 + l;
    int sB1 = 1*256 + w*64 + l;
    const bf16* gA0 = A + (size_t)(m0 + (sA0>>3))*K1_ + ((sA0&7) ^ ((sA0>>3)&7))*8;
    const bf16* gA1 = A + (size_t)(m0 + (sA1>>3))*K1_ + ((sA1&7) ^ ((sA1>>3)&7))*8;
    const bf16* gA2 = A + (size_t)(m0 + (sA2>>3))*K1_ + ((sA2&7) ^ ((sA2>>3)&7))*8;
    const bf16* gA3 = A + (size_t)(m0 + (sA3>>3))*K1_ + ((sA3&7) ^ ((sA3>>3)&7))*8;
    const bf16* gB0 = Bw + (size_t)(n0 + (sB0>>3))*K1_ + ((sB0&7) ^ ((sB0>>3)&7))*8;
    const bf16* gB1 = Bw + (size_t)(n0 + (sB1>>3))*K1_ + ((sB1&7) ^ ((sB1>>3)&7))*8;
    bf16* lA0 = &As[(0*256 + w*64)*8];
    bf16* lA1 = &As[(1*256 + w*64)*8];
    bf16* lA2 = &As[(2*256 + w*64)*8];
    bf16* lA3 = &As[(3*256 + w*64)*8];
    bf16* lB0 = &Bs[(0*256 + w*64)*8];
    bf16* lB1 = &Bs[(1*256 + w*64)*8];

    for(int k0 = 0; k0 < K1_; k0 += 64){
        GLD16(gA0 + k0, lA0);
        GLD16(gA1 + k0, lA1);
        GLD16(gA2 + k0, lA2);
        GLD16(gA3 + k0, lA3);
        GLD16(gB0 + k0, lB0);
        GLD16(gB1 + k0, lB1);
        __syncthreads();
        short8 af[2][4], bfr[2][2];
        #pragma unroll
        for(int kh = 0; kh < 2; ++kh){
            #pragma unroll
            for(int m = 0; m < 4; ++m){
                int row = wr*64 + m*16 + r;
                int e = (row*64 + kh*32 + kg*8) ^ ((r & 7) << 3);
                af[kh][m] = *(const short8*)&As[e];
            }
            #pragma unroll
            for(int n = 0; n < 2; ++n){
                int row = wc*32 + n*16 + r;
                int e = (row*64 + kh*32 + kg*8) ^ ((r & 7) << 3);
                bfr[kh][n] = *(const short8*)&Bs[e];
            }
        }
        #pragma unroll
        for(int kh = 0; kh < 2; ++kh)
            #pragma unroll
            for(int m = 0; m < 4; ++m)
                #pragma unroll
                for(int n = 0; n < 2; ++n)
                    acc[m][n] = __builtin_amdgcn_mfma_f32_16x16x32_bf16(
                                    af[kh][m], bfr[kh][n], acc[m][n], 0, 0, 0);
        __syncthreads();
    }
    // C/D layout: col = lane&15, row = (lane>>4)*4 + i   [m89]
    #pragma unroll
    for(int m = 0; m < 4; ++m){
        int rowb = m0 + wr*64 + m*16 + kg*4;
        #pragma unroll
        for(int n = 0; n < 2; ++n){
            int col = n0 + wc*32 + n*16 + r;
            float bv = bias[col];
            #pragma unroll
            for(int i = 0; i < 4; ++i)
                C[(size_t)(rowb + i)*D4_ + col] = acc[m][n][i] + bv;
        }
    }
}

// -------------------------------------- per-channel sum / sumsq over M rows
__global__ void k_stats(const float* __restrict__ X, int C, float* __restrict__ ST){
    int r0 = blockIdx.x * 32;
    int tid = threadIdx.x;
    for(int c = tid; c < C; c += 256){
        float s = 0.f, q = 0.f;
        for(int r = 0; r < 32; ++r){
            float v = X[(size_t)(r0 + r)*C + c];
            s += v;
            q = fmaf(v, v, q);
        }
        atomicAdd(&ST[c], s);
        atomicAdd(&ST[C + c], q);
    }
}

__global__ void k_bnfin(const float* __restrict__ ST, const float* __restrict__ g,
                        const float* __restrict__ bb, int C, float* __restrict__ P){
    int c = blockIdx.x * blockDim.x + threadIdx.x;
    if(c < C){
        float mu  = ST[c] * (1.0f / M_);
        float var = ST[C + c] * (1.0f / M_) - mu*mu;
        float sc  = g[c] * rsqrtf(var + 1e-5f);
        P[c]     = sc;
        P[C + c] = bb[c] - mu*sc;
    }
}

// ------- y2 = gelu(BN1(y1)) @ W2^T + b2 ; MFMA 64x64, BK=64, fused BN+gelu on A
__global__ __launch_bounds__(256) void k_gemm2(const float* __restrict__ Y1,
        const float* __restrict__ P1, const bf16* __restrict__ W2b,
        const float* __restrict__ b2, float* __restrict__ Z){
    __shared__ __align__(16) bf16 As[64*64];     // 8 KB
    __shared__ __align__(16) bf16 Bs[64*64];     // 8 KB
    int m0 = blockIdx.x * 64, n0 = blockIdx.y * 64;
    int tid = threadIdx.x;
    int w = tid >> 6, l = tid & 63;
    int wr = w >> 1, wc = w & 1;                 // wave -> 32x32 sub-tile
    int r = l & 15, kg = l >> 4;
    f32x4 acc[2][2] = {};

    // B staging via GLD16, pre-swizzled source (same recipe as k_gemm1)
    int sB0 = 0*256 + w*64 + l;
    int sB1 = 1*256 + w*64 + l;
    const bf16* gB0 = W2b + (size_t)(n0 + (sB0>>3))*D4_ + ((sB0&7) ^ ((sB0>>3)&7))*8;
    const bf16* gB1 = W2b + (size_t)(n0 + (sB1>>3))*D4_ + ((sB1&7) ^ ((sB1>>3)&7))*8;
    bf16* lB0 = &Bs[(0*256 + w*64)*8];
    bf16* lB1 = &Bs[(1*256 + w*64)*8];

    // A transform: thread covers row=tid>>2, 16 k at (tid&3)*16
    int arow = tid >> 2;
    int akq  = (tid & 3) * 16;
    int k8a  = (tid & 3) * 2;
    int e0 = arow*64 + ((k8a+0) ^ (arow & 7))*8;
    int e1 = arow*64 + ((k8a+1) ^ (arow & 7))*8;

    for(int k0 = 0; k0 < D4_; k0 += 64){
        GLD16(gB0 + k0, lB0);
        GLD16(gB1 + k0, lB1);
        const float* ya = &Y1[(size_t)(m0 + arow)*D4_ + k0 + akq];
        const float* sc = &P1[k0 + akq];
        const float* sh = &P1[D4_ + k0 + akq];
        unsigned int pk[8];
        #pragma unroll
        for(int q = 0; q < 4; ++q){
            float4 y  = *(const float4*)&ya[q*4];
            float4 s4 = *(const float4*)&sc[q*4];
            float4 h4 = *(const float4*)&sh[q*4];
            float a0 = gelu_f(fmaf(y.x, s4.x, h4.x));
            float a1 = gelu_f(fmaf(y.y, s4.y, h4.y));
            float a2 = gelu_f(fmaf(y.z, s4.z, h4.z));
            float a3 = gelu_f(fmaf(y.w, s4.w, h4.w));
            pk[q*2+0] = (unsigned)bf16_bits(a0) | ((unsigned)bf16_bits(a1) << 16);
            pk[q*2+1] = (unsigned)bf16_bits(a2) | ((unsigned)bf16_bits(a3) << 16);
        }
        uint4 wA0 = {pk[0], pk[1], pk[2], pk[3]};
        uint4 wA1 = {pk[4], pk[5], pk[6], pk[7]};
        *(uint4*)&As[e0] = wA0;
        *(uint4*)&As[e1] = wA1;
        __syncthreads();             // drains vmcnt (GLD16) + lgkm (ds_write)
        short8 af[2][2], bfr[2][2];
        #pragma unroll
        for(int kh = 0; kh < 2; ++kh){
            #pragma unroll
            for(int m = 0; m < 2; ++m){
                int row = wr*32 + m*16 + r;
                int e = (row*64 + kh*32 + kg*8) ^ ((r & 7) << 3);
                af[kh][m] = *(const short8*)&As[e];
            }
            #pragma unroll
            for(int n = 0; n < 2; ++n){
                int row = wc*32 + n*16 + r;
                int e = (row*64 + kh*32 + kg*8) ^ ((r & 7) << 3);
                bfr[kh][n] = *(const short8*)&Bs[e];
            }
        }
        #pragma unroll
        for(int kh = 0; kh < 2; ++kh)
            #pragma unroll
            for(int m = 0; m < 2; ++m)
                #pragma unroll
                for(int n = 0; n < 2; ++n)
                    acc[m][n] = __builtin_amdgcn_mfma_f32_16x16x32_bf16(
                                    af[kh][m], bfr[kh][n], acc[m][n], 0, 0, 0);
        __syncthreads();
    }
    #pragma unroll
    for(int m = 0; m < 2; ++m){
        int rowb = m0 + wr*32 + m*16 + kg*4;
        #pragma unroll
        for(int n = 0; n < 2; ++n){
            int col = n0 + wc*32 + n*16 + r;
            float bv = b2[col];
            #pragma unroll
            for(int i = 0; i < 4; ++i)
                Z[(size_t)(rowb + i)*D_ + col] = acc[m][n][i] + bv;
        }
    }
}

// ------- z = gelu(BN2(y2)); LN over d; out[b,o,t] = z + zn (t-contig float4)
__global__ __launch_bounds__(256) void k_final(const float* __restrict__ Z,
        const float* __restrict__ P2, const float* __restrict__ lng,
        const float* __restrict__ lnb, float* __restrict__ out){
    __shared__ float s_z[64*129];
    __shared__ float s_mu[64];
    __shared__ float s_rs[64];
    int b  = blockIdx.x >> 2;
    int t0 = (blockIdx.x & 3) * 64;
    int tid = threadIdx.x;
    #pragma unroll
    for(int i = 0; i < 32; ++i){
        int idx = tid + i*256;
        int row = idx >> 7, col = idx & 127;
        float v = Z[(size_t)(b*T_ + t0 + row)*D_ + col];
        s_z[row*129 + col] = gelu_f(fmaf(v, P2[col], P2[D_ + col]));
    }
    __syncthreads();
    if(tid < 64){
        float s = 0.f;
        #pragma unroll
        for(int j = 0; j < D_; ++j) s += s_z[tid*129 + j];
        float mu = s * (1.0f / D_);
        float q = 0.f;
        #pragma unroll
        for(int j = 0; j < D_; ++j){
            float dv = s_z[tid*129 + j] - mu;
            q = fmaf(dv, dv, q);
        }
        s_mu[tid] = mu;
        s_rs[tid] = rsqrtf(q * (1.0f / D_) + 1e-5f);
    }
    __syncthreads();
    int o  = tid & 127;
    int th = tid >> 7;               // 0/1 -> t-half of the 64-row tile
    float g  = lng[o];
    float be = lnb[o];
    #pragma unroll
    for(int j4 = 0; j4 < 8; ++j4){
        float4 ov;
        #pragma unroll
        for(int q = 0; q < 4; ++q){
            int tt = th*32 + j4*4 + q;
            float z = s_z[tt*129 + o];
            float zn = fmaf((z - s_mu[tt]) * s_rs[tt], g, be);
            (&ov.x)[q] = z + zn;
        }
        *(float4*)&out[((size_t)(b*D_ + o))*T_ + t0 + th*32 + j4*4] = ov;
    }
}

extern "C" void kernel_launch(void* const* d_in, const int* in_sizes, int n_in,
                              void* d_out, int out_size, void* d_ws, size_t ws_size,
                              hipStream_t stream){
    const float* Xtemp   = (const float*)d_in[0];
    const float* Xtimes  = (const float*)d_in[1];
    const float* Xstatic = (const float*)d_in[2];
    const int*   mask    = (const int*)  d_in[3];
    const float* Wq      = (const float*)d_in[4];
    const float* Wk      = (const float*)d_in[5];
    const float* Wv      = (const float*)d_in[6];
    const float* tempW   = (const float*)d_in[7];
    const float* tempB   = (const float*)d_in[8];
    const float* embW    = (const float*)d_in[9];
    const float* embB    = (const float*)d_in[10];
    const float* W1      = (const float*)d_in[11];
    const float* b1      = (const float*)d_in[12];
    const float* bn1g    = (const float*)d_in[13];
    const float* bn1b    = (const float*)d_in[14];
    const float* W2      = (const float*)d_in[15];
    const float* b2      = (const float*)d_in[16];
    const float* bn2g    = (const float*)d_in[17];
    const float* bn2b    = (const float*)d_in[18];
    const float* lng     = (const float*)d_in[19];
    const float* lnb     = (const float*)d_in[20];
    float* out = (float*)d_out;

    float* w = (float*)d_ws;
    float* PE = w;  w += (size_t)M_ * D_;            // 1,048,576 f32
    float* CB = w;  w += (size_t)B_ * V_ * D_;       // 147,456
    float* cbP= w;  w += (size_t)B_ * 9 * D_ * 4;    // 147,456
    float* twP= w;  w += (size_t)9 * D_ * 4;         // 4,608
    float* H4 = w;  w += (size_t)B_ * V_ * D_;
    float* QS = w;  w += (size_t)B_ * V_ * D_;
    float* KS = w;  w += (size_t)B_ * V_ * D_;
    float* MV = w;  w += (size_t)B_ * V_ * D_;
    float* E  = w;  w += (size_t)B_ * 144 * 40;      // 184,320 (padded rows)
    float* QQ = w;  w += (size_t)M_ * 80;            // 655,360
    float* RD = w;  w += (size_t)M_ * 144;           // 1,179,648 (4.7 MB)
    float* Y1 = w;  w += (size_t)M_ * D4_;           // 4,194,304
    float* Z1 = w;  w += (size_t)M_ * D_;            // 1,048,576
    float* ST1 = w; w += 1024;
    float* ST2 = w; w += 256;
    float* P1  = w; w += 1024;
    float* P2  = w; w += 256;
    bf16* V5  = (bf16*)w;                            // 75.5 MB
    bf16* W1b = V5 + (size_t)M_ * K1_;               // 4.7 MB
    bf16* W2b = W1b + (size_t)D4_ * K1_;             // 128 KB

    hipMemsetAsync(ST1, 0, (1024 + 256) * sizeof(float), stream);

    k_pe    <<<M_, D_, 0, stream>>>(Xtimes, Xtemp, mask, PE, QQ);
    k_cb    <<<B_*V_, D_, 0, stream>>>(Xstatic, embW, embB, tempB, CB, cbP);
    k_packtw<<<V_, D_, 0, stream>>>(tempW, twP);
    k_castw1<<<(D4_*K1_)/256, 256, 0, stream>>>(W1, W1b);
    k_cast  <<<(D_*D4_)/1024, 256, 0, stream>>>(W2, W2b);
    k_h4    <<<B_*V_, 256, 0, stream>>>(Xtemp, mask, PE, tempW, CB, H4);
    k_qkv   <<<B_*V_, D_, 0, stream>>>(H4, Wq, Wk, Wv, QS, KS, MV);
    k_attE  <<<B_*H_*V_, 64, 0, stream>>>(QS, KS, E);
    k_den   <<<M_, 192, 0, stream>>>(E, QQ, RD);
    k_v5    <<<B_*(T_/8), 256, 0, stream>>>(QQ, E, twP, cbP, MV, PE, RD, V5);
    k_gemm1 <<<512, 256, 0, stream>>>(V5, W1b, b1, Y1);
    k_stats <<<M_/32, 256, 0, stream>>>(Y1, D4_, ST1);
    k_bnfin <<<2, 256, 0, stream>>>(ST1, bn1g, bn1b, D4_, P1);
    k_gemm2 <<<dim3(M_/64, D_/64), 256, 0, stream>>>(Y1, P1, W2b, b2, Z1);
    k_stats <<<M_/32, 256, 0, stream>>>(Z1, D_, ST2);
    k_bnfin <<<1, 128, 0, stream>>>(ST2, bn2g, bn2b, D_, P2);
    k_final <<<B_*(T_/64), 256, 0, stream>>>(Z1, P2, lng, lnb, out);
}